// Round 1
// baseline (360.623 us; speedup 1.0000x reference)
//
#include <hip/hip_runtime.h>
#include <cstdint>
#include <cmath>

#define KDIM    1024
#define DPROJ   4384
#define NPAD    4480   // 4384 padded to 35*128
#define CONVDIM 2304
#define SEQ     2048
#define BATCH   2
#define MROWS   4096   // BATCH*SEQ
#define NHEADS  32
#define HEADDIM 64
#define DSTATE  128
#define CHUNK   256
#define NCHUNK  8
#define DINNER  2048
#define EPS     1e-5f

typedef unsigned short u16;
typedef float  f32x4  __attribute__((ext_vector_type(4)));
typedef __bf16 bf16x8 __attribute__((ext_vector_type(8)));

__device__ __forceinline__ u16 f2bf(float f){
  unsigned u = __builtin_bit_cast(unsigned, f);
  u += 0x7fffu + ((u >> 16) & 1u);   // RNE
  return (u16)(u >> 16);
}
__device__ __forceinline__ float bf2f(u16 s){
  unsigned u = ((unsigned)s) << 16;
  return __builtin_bit_cast(float, u);
}
__device__ __forceinline__ void gl_lds16(const void* g, void* l){
  // async global->LDS, 16B per lane; LDS dest is wave-uniform base + lane*16
  __builtin_amdgcn_global_load_lds((const __attribute__((address_space(1))) void*)g,
                                   (__attribute__((address_space(3))) void*)l, 16, 0, 0);
}
__device__ __forceinline__ float sigmoidf_(float x){ return 1.f / (1.f + expf(-x)); }

// ---------------- dtype conversion kernels ----------------
__global__ __launch_bounds__(256) void k_cvt_u(const float* __restrict__ in, u16* __restrict__ out){
  size_t i = ((size_t)blockIdx.x * 256 + threadIdx.x) * 4;
  float4 v = *(const float4*)(in + i);
  unsigned a = (unsigned)f2bf(v.x) | ((unsigned)f2bf(v.y) << 16);
  unsigned b = (unsigned)f2bf(v.z) | ((unsigned)f2bf(v.w) << 16);
  uint2 o; o.x = a; o.y = b;
  *(uint2*)(out + i) = o;
}

__global__ __launch_bounds__(256) void k_cvt_w(const float* __restrict__ in, u16* __restrict__ out){
  size_t i = ((size_t)blockIdx.x * 256 + threadIdx.x) * 4;
  int row = (int)(i >> 10);
  float4 v = make_float4(0.f,0.f,0.f,0.f);
  if(row < DPROJ) v = *(const float4*)(in + i);
  unsigned a = (unsigned)f2bf(v.x) | ((unsigned)f2bf(v.y) << 16);
  unsigned b = (unsigned)f2bf(v.z) | ((unsigned)f2bf(v.w) << 16);
  uint2 o; o.x = a; o.y = b;
  *(uint2*)(out + i) = o;
}

// ---------------- in-projection GEMM: zxbcdt = u @ W^T ----------------
// A: (4096 x 1024) bf16 row-major, B: (4480 x 1024) bf16 row-major (= W^T form)
// C: (4096 x 4480) fp32. m97-style: 128x128 tile, BK=32, 4 waves of 64x64.
__global__ __launch_bounds__(256) void k_gemm(const u16* __restrict__ A, const u16* __restrict__ B,
                                              float* __restrict__ C){
  __shared__ u16 As[128*32];
  __shared__ u16 Bs[128*32];
  int tid = threadIdx.x;
  int m0 = blockIdx.y * 128, n0 = blockIdx.x * 128;
  int w = tid >> 6, lane = tid & 63, r = lane & 15, q = lane >> 4;
  int wm = (w >> 1) * 64, wn = (w & 1) * 64;
  f32x4 acc[4][4] = {};
  const u16* Ag0 = A + (size_t)(m0 +       (tid >> 2)) * KDIM + (tid & 3) * 8;
  const u16* Ag1 = A + (size_t)(m0 + 64 +  (tid >> 2)) * KDIM + (tid & 3) * 8;
  const u16* Bg0 = B + (size_t)(n0 +       (tid >> 2)) * KDIM + (tid & 3) * 8;
  const u16* Bg1 = B + (size_t)(n0 + 64 +  (tid >> 2)) * KDIM + (tid & 3) * 8;
  for(int kt = 0; kt < KDIM/32; kt++){
    int k0 = kt * 32;
    gl_lds16(Ag0 + k0, &As[(size_t)tid * 8]);
    gl_lds16(Ag1 + k0, &As[((size_t)tid + 256) * 8]);
    gl_lds16(Bg0 + k0, &Bs[(size_t)tid * 8]);
    gl_lds16(Bg1 + k0, &Bs[((size_t)tid + 256) * 8]);
    __syncthreads();   // drains vmcnt before barrier
    bf16x8 af[4], bfm[4];
    #pragma unroll
    for(int i = 0; i < 4; i++) af[i]  = *(const bf16x8*)&As[(wm + i*16 + r) * 32 + q*8];
    #pragma unroll
    for(int j = 0; j < 4; j++) bfm[j] = *(const bf16x8*)&Bs[(wn + j*16 + r) * 32 + q*8];
    #pragma unroll
    for(int i = 0; i < 4; i++)
      #pragma unroll
      for(int j = 0; j < 4; j++)
        acc[i][j] = __builtin_amdgcn_mfma_f32_16x16x32_bf16(af[i], bfm[j], acc[i][j], 0, 0, 0);
    __syncthreads();
  }
  #pragma unroll
  for(int i = 0; i < 4; i++)
    #pragma unroll
    for(int j = 0; j < 4; j++)
      #pragma unroll
      for(int e = 0; e < 4; e++){
        int row = m0 + wm + i*16 + q*4 + e;
        int col = n0 + wn + j*16 + r;
        C[(size_t)row * NPAD + col] = acc[i][j][e];
      }
}

// ---------------- conv1d (causal, depthwise, width 4) + silu + split ----------------
__global__ __launch_bounds__(256) void k_conv(const float* __restrict__ zx,
                                              const float* __restrict__ cw,
                                              const float* __restrict__ cb,
                                              u16* __restrict__ xq, u16* __restrict__ Bq,
                                              u16* __restrict__ Cq){
  size_t i = (size_t)blockIdx.x * 256 + threadIdx.x;   // over BATCH*SEQ*CONVDIM
  int c  = (int)(i % CONVDIM);
  int bl = (int)(i / CONVDIM);
  int l  = bl & (SEQ - 1);
  float acc = cb[c];
  #pragma unroll
  for(int k = 0; k < 4; k++){
    int t = l + k - 3;
    float v = (t >= 0) ? zx[(size_t)(bl + k - 3) * NPAD + 2048 + c] : 0.f;
    acc += v * cw[c*4 + k];
  }
  float s = acc * sigmoidf_(acc);
  u16 sv = f2bf(s);
  if(c < DINNER)            xq[(size_t)bl * DINNER + c] = sv;
  else if(c < DINNER + 128) Bq[(size_t)bl * 128 + (c - DINNER)] = sv;
  else                      Cq[(size_t)bl * 128 + (c - DINNER - 128)] = sv;
}

// ---------------- dt = softplus(dt_raw + dt_bias) ----------------
__global__ __launch_bounds__(256) void k_dt(const float* __restrict__ zx,
                                            const float* __restrict__ dt_bias,
                                            float* __restrict__ dtb){
  size_t i = (size_t)blockIdx.x * 256 + threadIdx.x;  // over BATCH*SEQ*NHEADS
  int h  = (int)(i & 31);
  size_t bl = i >> 5;
  float v = zx[bl * NPAD + 4352 + h] + dt_bias[h];
  dtb[i] = (v > 20.f) ? v : log1pf(expf(v));
}

// ---------------- per-chunk cumsum of a = dt*A ----------------
__global__ __launch_bounds__(256) void k_acum(const float* __restrict__ dtb,
                                              const float* __restrict__ A_log,
                                              float* __restrict__ acum,
                                              float* __restrict__ cdec){
  int bid = blockIdx.x;               // (b*8+c)*32+h
  int h = bid & 31, c = (bid >> 5) & 7, b = bid >> 8;
  int t = threadIdx.x;
  __shared__ float sb[256];
  float Ah = -expf(A_log[h]);
  float a = dtb[(size_t)(b*SEQ + c*CHUNK + t) * 32 + h] * Ah;
  sb[t] = a; __syncthreads();
  for(int off = 1; off < 256; off <<= 1){
    float v = (t >= off) ? sb[t - off] : 0.f;
    __syncthreads();
    sb[t] += v;
    __syncthreads();
  }
  float ac = sb[t];
  acum[(size_t)bid * 256 + t] = ac;
  if(t == 255) cdec[bid] = expf(ac);
}

// ---------------- chunk-final states: states(p,n) = sum_l B(l,n)*ds(l)*x(l,p)*dt(l) ----------------
__global__ __launch_bounds__(256) void k_states(const u16* __restrict__ xq, const u16* __restrict__ Bq,
                                                const float* __restrict__ dtb,
                                                const float* __restrict__ acum,
                                                float* __restrict__ states){
  int bid = blockIdx.x;               // (b*8+c)*32+h
  int h = bid & 31, c = (bid >> 5) & 7, b = bid >> 8;
  int tid = threadIdx.x;
  int w = tid >> 6, lane = tid & 63, r = lane & 15, q = lane >> 4;
  __shared__ u16 xT[64*72];           // [p][l] transposed, +8 pad
  __shared__ u16 bT[128*72];          // [n][l] transposed (B*decay)
  __shared__ float dss[64], dtt[64];
  size_t rowB = (size_t)(b*SEQ + c*CHUNK);
  float alast = acum[(size_t)bid * 256 + 255];
  f32x4 acc[4][2] = {};
  for(int slab = 0; slab < 4; slab++){
    int lb = slab * 64;
    if(tid < 64){
      float ac = acum[(size_t)bid * 256 + lb + tid];
      dss[tid] = expf(alast - ac);
      dtt[tid] = dtb[(rowB + lb + tid) * 32 + h];
    }
    __syncthreads();
    for(int it = 0; it < 16; it++){                 // 64x64 x-slab, transposed
      int idx = it * 256 + tid; int p = idx & 63; int ll = idx >> 6;
      float v = bf2f(xq[(rowB + lb + ll) * DINNER + h*64 + p]) * dtt[ll];
      xT[p*72 + ll] = f2bf(v);
    }
    for(int it = 0; it < 32; it++){                 // 64x128 B-slab, transposed, decay folded
      int idx = it * 256 + tid; int n = idx & 127; int ll = idx >> 7;
      float v = bf2f(Bq[(rowB + lb + ll) * 128 + n]) * dss[ll];
      bT[n*72 + ll] = f2bf(v);
    }
    __syncthreads();
    #pragma unroll
    for(int ks = 0; ks < 2; ks++){
      bf16x8 af[4], bfr[2];
      #pragma unroll
      for(int i = 0; i < 4; i++) af[i]  = *(const bf16x8*)&xT[(i*16 + r)*72 + ks*32 + q*8];
      #pragma unroll
      for(int j = 0; j < 2; j++) bfr[j] = *(const bf16x8*)&bT[(w*32 + j*16 + r)*72 + ks*32 + q*8];
      #pragma unroll
      for(int i = 0; i < 4; i++)
        #pragma unroll
        for(int j = 0; j < 2; j++)
          acc[i][j] = __builtin_amdgcn_mfma_f32_16x16x32_bf16(af[i], bfr[j], acc[i][j], 0, 0, 0);
    }
    __syncthreads();
  }
  #pragma unroll
  for(int i = 0; i < 4; i++)
    #pragma unroll
    for(int j = 0; j < 2; j++)
      #pragma unroll
      for(int e = 0; e < 4; e++){
        int p = i*16 + q*4 + e;
        int n = w*32 + j*16 + r;
        states[((size_t)bid * 64 + p) * 128 + n] = acc[i][j][e];
      }
}

// ---------------- inter-chunk sequential scan ----------------
__global__ __launch_bounds__(256) void k_scan(const float* __restrict__ states,
                                              const float* __restrict__ cdec,
                                              float* __restrict__ prev){
  size_t i = (size_t)blockIdx.x * 256 + threadIdx.x;  // over BATCH*NHEADS*64*128
  int n = (int)(i & 127), p = (int)((i >> 7) & 63), h = (int)((i >> 13) & 31), b = (int)(i >> 18);
  float carry = 0.f;
  for(int c = 0; c < NCHUNK; c++){
    int bch = (b*8 + c)*32 + h;
    size_t off = ((size_t)bch * 64 + p) * 128 + n;
    float s = states[off];
    prev[off] = carry;
    carry = carry * cdec[bch] + s;
  }
}

// ---------------- Y = Y_off + Y_diag + D*x (one wave per (b,c,h,ltile)) ----------------
__global__ __launch_bounds__(64, 1) void k_y(const u16* __restrict__ xq, const u16* __restrict__ Bq,
                                             const u16* __restrict__ Cq, const float* __restrict__ dtb,
                                             const float* __restrict__ acum, const float* __restrict__ prev,
                                             const float* __restrict__ D_param, float* __restrict__ out){
  int bid = blockIdx.x;                 // ((b*8+c)*32+h)*4+lt
  int lt = bid & 3, h = (bid >> 2) & 31, c = (bid >> 7) & 7, b = bid >> 10;
  int bch = (b*8 + c)*32 + h;
  int t = threadIdx.x, r = t & 15, q = t >> 4;
  int l0 = lt * 64;
  __shared__ float acl[256];
  __shared__ float dts[256];
  __shared__ u16 G[64*72];
  __shared__ u16 xT[64*72];
  for(int it = 0; it < 4; it++){
    int s = it*64 + t;
    acl[s] = acum[(size_t)bch * 256 + s];
    dts[s] = dtb[(size_t)(b*SEQ + c*CHUNK + s) * 32 + h];
  }
  __syncthreads();
  size_t rowC = (size_t)(b*SEQ + c*CHUNK);
  // C fragments: reused across off-GEMM and all s-tiles
  bf16x8 cf[4][4];
  #pragma unroll
  for(int i = 0; i < 4; i++)
    #pragma unroll
    for(int ks = 0; ks < 4; ks++)
      cf[i][ks] = *(const bf16x8*)&Cq[(rowC + l0 + i*16 + r) * 128 + ks*32 + q*8];
  // Y_off = C . prev^T
  f32x4 accY[4][4] = {};
  #pragma unroll
  for(int ks = 0; ks < 4; ks++){
    #pragma unroll
    for(int j = 0; j < 4; j++){
      const float* pp = prev + ((size_t)bch * 64 + j*16 + r) * 128 + ks*32 + q*8;
      float4 v0 = *(const float4*)pp;
      float4 v1 = *(const float4*)(pp + 4);
      bf16x8 bf;
      bf[0]=(__bf16)v0.x; bf[1]=(__bf16)v0.y; bf[2]=(__bf16)v0.z; bf[3]=(__bf16)v0.w;
      bf[4]=(__bf16)v1.x; bf[5]=(__bf16)v1.y; bf[6]=(__bf16)v1.z; bf[7]=(__bf16)v1.w;
      #pragma unroll
      for(int i = 0; i < 4; i++)
        accY[i][j] = __builtin_amdgcn_mfma_f32_16x16x32_bf16(cf[i][ks], bf, accY[i][j], 0, 0, 0);
    }
  }
  // scale rows by exp(acum[l])
  #pragma unroll
  for(int i = 0; i < 4; i++)
    #pragma unroll
    for(int e = 0; e < 4; e++){
      float sc = expf(acl[l0 + i*16 + q*4 + e]);
      #pragma unroll
      for(int j = 0; j < 4; j++) accY[i][j][e] *= sc;
    }
  // diagonal blocks: S = C.B^T, G = mask.decay(S), Y += G.xdt
  for(int st = 0; st <= lt; st++){
    int s0 = st * 64;
    f32x4 accS[4][4] = {};
    #pragma unroll
    for(int ks = 0; ks < 4; ks++){
      #pragma unroll
      for(int j = 0; j < 4; j++){
        bf16x8 bfr = *(const bf16x8*)&Bq[(rowC + s0 + j*16 + r) * 128 + ks*32 + q*8];
        #pragma unroll
        for(int i = 0; i < 4; i++)
          accS[i][j] = __builtin_amdgcn_mfma_f32_16x16x32_bf16(cf[i][ks], bfr, accS[i][j], 0, 0, 0);
      }
    }
    __syncthreads();   // previous iteration's LDS reads complete before overwrite
    #pragma unroll
    for(int i = 0; i < 4; i++)
      #pragma unroll
      for(int j = 0; j < 4; j++)
        #pragma unroll
        for(int e = 0; e < 4; e++){
          int ll = l0 + i*16 + q*4 + e;
          int ss = s0 + j*16 + r;
          float v = (ll >= ss) ? accS[i][j][e] * expf(acl[ll] - acl[ss]) : 0.f;
          G[(i*16 + q*4 + e)*72 + j*16 + r] = f2bf(v);
        }
    for(int i2 = 0; i2 < 64; i2++){     // stage xdt^T (p-major)
      float v = bf2f(xq[(rowC + s0 + i2) * DINNER + h*64 + t]) * dts[s0 + i2];
      xT[t*72 + i2] = f2bf(v);
    }
    __syncthreads();
    #pragma unroll
    for(int ks = 0; ks < 2; ks++){
      bf16x8 gf[4], xf[4];
      #pragma unroll
      for(int i = 0; i < 4; i++) gf[i] = *(const bf16x8*)&G[(i*16 + r)*72 + ks*32 + q*8];
      #pragma unroll
      for(int j = 0; j < 4; j++) xf[j] = *(const bf16x8*)&xT[(j*16 + r)*72 + ks*32 + q*8];
      #pragma unroll
      for(int i = 0; i < 4; i++)
        #pragma unroll
        for(int j = 0; j < 4; j++)
          accY[i][j] = __builtin_amdgcn_mfma_f32_16x16x32_bf16(gf[i], xf[j], accY[i][j], 0, 0, 0);
    }
  }
  // epilogue: + D*x, write Y
  float Dh = D_param[h];
  #pragma unroll
  for(int i = 0; i < 4; i++)
    #pragma unroll
    for(int j = 0; j < 4; j++)
      #pragma unroll
      for(int e = 0; e < 4; e++){
        int ll = l0 + i*16 + q*4 + e;
        int p = j*16 + r;
        float xv = bf2f(xq[(rowC + ll) * DINNER + h*64 + p]);
        out[(rowC + ll) * (size_t)DINNER + h*64 + p] = accY[i][j][e] + Dh * xv;
      }
}

// ---------------- gated RMSNorm (in-place on out, z from zxbcdt) ----------------
__global__ __launch_bounds__(256) void k_norm(float* __restrict__ out, const float* __restrict__ zx,
                                              const float* __restrict__ nw){
  int bl = blockIdx.x;
  int t = threadIdx.x;
  float g[8];
  float ss = 0.f;
  #pragma unroll
  for(int it = 0; it < 8; it++){
    int cidx = it*256 + t;
    float y = out[(size_t)bl * DINNER + cidx];
    float z = zx[(size_t)bl * NPAD + cidx];
    float v = y * (z * sigmoidf_(z));
    g[it] = v;
    ss += v * v;
  }
  #pragma unroll
  for(int off = 32; off > 0; off >>= 1) ss += __shfl_down(ss, off, 64);
  __shared__ float wsum[4];
  if((t & 63) == 0) wsum[t >> 6] = ss;
  __syncthreads();
  float tot = wsum[0] + wsum[1] + wsum[2] + wsum[3];
  float scale = rsqrtf(tot / (float)DINNER + EPS);
  #pragma unroll
  for(int it = 0; it < 8; it++){
    int cidx = it*256 + t;
    out[(size_t)bl * DINNER + cidx] = g[it] * scale * nw[cidx];
  }
}

extern "C" void kernel_launch(void* const* d_in, const int* in_sizes, int n_in,
                              void* d_out, int out_size, void* d_ws, size_t ws_size,
                              hipStream_t stream){
  const float* u    = (const float*)d_in[0];
  const float* W    = (const float*)d_in[1];
  const float* cw   = (const float*)d_in[2];
  const float* cb   = (const float*)d_in[3];
  const float* dtbi = (const float*)d_in[4];
  const float* Alog = (const float*)d_in[5];
  const float* Dp   = (const float*)d_in[6];
  const float* nw   = (const float*)d_in[7];
  float* out = (float*)d_out;

  char* ws = (char*)d_ws;
  size_t off = 0;
  auto alloc = [&](size_t bytes) -> void* {
    void* p = ws + off;
    off += (bytes + 255) & ~(size_t)255;
    return p;
  };
  u16*   u_bf    = (u16*)  alloc((size_t)MROWS * KDIM * 2);       //  8.4 MB
  u16*   W_bf    = (u16*)  alloc((size_t)NPAD * KDIM * 2);        //  9.2 MB
  float* zxbcdt  = (float*)alloc((size_t)MROWS * NPAD * 4);       // 73.4 MB
  u16*   xq      = (u16*)  alloc((size_t)MROWS * DINNER * 2);     // 16.8 MB
  u16*   Bq      = (u16*)  alloc((size_t)MROWS * 128 * 2);        //  1.0 MB
  u16*   Cq      = (u16*)  alloc((size_t)MROWS * 128 * 2);        //  1.0 MB
  float* dtb     = (float*)alloc((size_t)MROWS * 32 * 4);         //  0.5 MB
  float* acum    = (float*)alloc((size_t)512 * 256 * 4);          //  0.5 MB
  float* cdec    = (float*)alloc((size_t)512 * 4);
  float* states  = (float*)alloc((size_t)512 * 64 * 128 * 4);     // 16.8 MB
  float* prev    = (float*)alloc((size_t)512 * 64 * 128 * 4);     // 16.8 MB

  k_cvt_u<<<(MROWS*KDIM)/(256*4), 256, 0, stream>>>(u, u_bf);
  k_cvt_w<<<((size_t)NPAD*KDIM)/(256*4), 256, 0, stream>>>(W, W_bf);
  k_gemm<<<dim3(NPAD/128, MROWS/128), 256, 0, stream>>>(u_bf, W_bf, zxbcdt);
  k_conv<<<((size_t)MROWS*CONVDIM)/256, 256, 0, stream>>>(zxbcdt, cw, cb, xq, Bq, Cq);
  k_dt<<<((size_t)MROWS*32)/256, 256, 0, stream>>>(zxbcdt, dtbi, dtb);
  k_acum<<<512, 256, 0, stream>>>(dtb, Alog, acum, cdec);
  k_states<<<512, 256, 0, stream>>>(xq, Bq, dtb, acum, states);
  k_scan<<<((size_t)BATCH*NHEADS*64*128)/256, 256, 0, stream>>>(states, cdec, prev);
  k_y<<<2048, 64, 0, stream>>>(xq, Bq, Cq, dtb, acum, prev, Dp, out);
  k_norm<<<MROWS, 256, 0, stream>>>(out, zxbcdt, nw);
}

// Round 2
// 327.565 us; speedup vs baseline: 1.1009x; 1.1009x over previous
//
#include <hip/hip_runtime.h>
#include <cstdint>
#include <cmath>

#define KDIM    1024
#define DPROJ   4384
#define NPAD    4480   // 4384 padded to 35*128
#define CONVDIM 2304
#define SEQ     2048
#define BATCH   2
#define MROWS   4096   // BATCH*SEQ
#define NHEADS  32
#define HEADDIM 64
#define DSTATE  128
#define CHUNK   256
#define NCHUNK  8
#define DINNER  2048
#define EPS     1e-5f

typedef unsigned short u16;
typedef float  f32x4  __attribute__((ext_vector_type(4)));
typedef __bf16 bf16x8 __attribute__((ext_vector_type(8)));
typedef u16    u16x8  __attribute__((ext_vector_type(8)));

__device__ __forceinline__ u16 f2bf(float f){
  unsigned u = __builtin_bit_cast(unsigned, f);
  u += 0x7fffu + ((u >> 16) & 1u);   // RNE
  return (u16)(u >> 16);
}
__device__ __forceinline__ float bf2f(u16 s){
  unsigned u = ((unsigned)s) << 16;
  return __builtin_bit_cast(float, u);
}
__device__ __forceinline__ void gl_lds16(const void* g, void* l){
  __builtin_amdgcn_global_load_lds((const __attribute__((address_space(1))) void*)g,
                                   (__attribute__((address_space(3))) void*)l, 16, 0, 0);
}
__device__ __forceinline__ float sigmoidf_(float x){ return 1.f / (1.f + expf(-x)); }

// ---------------- dtype conversion kernels ----------------
__global__ __launch_bounds__(256) void k_cvt_u(const float* __restrict__ in, u16* __restrict__ out){
  size_t i = ((size_t)blockIdx.x * 256 + threadIdx.x) * 4;
  float4 v = *(const float4*)(in + i);
  unsigned a = (unsigned)f2bf(v.x) | ((unsigned)f2bf(v.y) << 16);
  unsigned b = (unsigned)f2bf(v.z) | ((unsigned)f2bf(v.w) << 16);
  uint2 o; o.x = a; o.y = b;
  *(uint2*)(out + i) = o;
}

__global__ __launch_bounds__(256) void k_cvt_w(const float* __restrict__ in, u16* __restrict__ out){
  size_t i = ((size_t)blockIdx.x * 256 + threadIdx.x) * 4;
  int row = (int)(i >> 10);
  float4 v = make_float4(0.f,0.f,0.f,0.f);
  if(row < DPROJ) v = *(const float4*)(in + i);
  unsigned a = (unsigned)f2bf(v.x) | ((unsigned)f2bf(v.y) << 16);
  unsigned b = (unsigned)f2bf(v.z) | ((unsigned)f2bf(v.w) << 16);
  uint2 o; o.x = a; o.y = b;
  *(uint2*)(out + i) = o;
}

// ---------------- in-projection GEMM: zxbcdt = u @ W^T ----------------
__global__ __launch_bounds__(256) void k_gemm(const u16* __restrict__ A, const u16* __restrict__ B,
                                              float* __restrict__ C){
  __shared__ u16 As[128*32];
  __shared__ u16 Bs[128*32];
  int tid = threadIdx.x;
  int m0 = blockIdx.y * 128, n0 = blockIdx.x * 128;
  int w = tid >> 6, lane = tid & 63, r = lane & 15, q = lane >> 4;
  int wm = (w >> 1) * 64, wn = (w & 1) * 64;
  f32x4 acc[4][4] = {};
  const u16* Ag0 = A + (size_t)(m0 +       (tid >> 2)) * KDIM + (tid & 3) * 8;
  const u16* Ag1 = A + (size_t)(m0 + 64 +  (tid >> 2)) * KDIM + (tid & 3) * 8;
  const u16* Bg0 = B + (size_t)(n0 +       (tid >> 2)) * KDIM + (tid & 3) * 8;
  const u16* Bg1 = B + (size_t)(n0 + 64 +  (tid >> 2)) * KDIM + (tid & 3) * 8;
  for(int kt = 0; kt < KDIM/32; kt++){
    int k0 = kt * 32;
    gl_lds16(Ag0 + k0, &As[(size_t)tid * 8]);
    gl_lds16(Ag1 + k0, &As[((size_t)tid + 256) * 8]);
    gl_lds16(Bg0 + k0, &Bs[(size_t)tid * 8]);
    gl_lds16(Bg1 + k0, &Bs[((size_t)tid + 256) * 8]);
    __syncthreads();
    bf16x8 af[4], bfm[4];
    #pragma unroll
    for(int i = 0; i < 4; i++) af[i]  = *(const bf16x8*)&As[(wm + i*16 + r) * 32 + q*8];
    #pragma unroll
    for(int j = 0; j < 4; j++) bfm[j] = *(const bf16x8*)&Bs[(wn + j*16 + r) * 32 + q*8];
    #pragma unroll
    for(int i = 0; i < 4; i++)
      #pragma unroll
      for(int j = 0; j < 4; j++)
        acc[i][j] = __builtin_amdgcn_mfma_f32_16x16x32_bf16(af[i], bfm[j], acc[i][j], 0, 0, 0);
    __syncthreads();
  }
  #pragma unroll
  for(int i = 0; i < 4; i++)
    #pragma unroll
    for(int j = 0; j < 4; j++)
      #pragma unroll
      for(int e = 0; e < 4; e++){
        int row = m0 + wm + i*16 + q*4 + e;
        int col = n0 + wn + j*16 + r;
        C[(size_t)row * NPAD + col] = acc[i][j][e];
      }
}

// ---------------- conv1d (causal, depthwise, width 4) + silu + split ----------------
__global__ __launch_bounds__(256) void k_conv(const float* __restrict__ zx,
                                              const float* __restrict__ cw,
                                              const float* __restrict__ cb,
                                              u16* __restrict__ xq, u16* __restrict__ Bq,
                                              u16* __restrict__ Cq){
  size_t i = (size_t)blockIdx.x * 256 + threadIdx.x;
  int c  = (int)(i % CONVDIM);
  int bl = (int)(i / CONVDIM);
  int l  = bl & (SEQ - 1);
  float acc = cb[c];
  #pragma unroll
  for(int k = 0; k < 4; k++){
    int t = l + k - 3;
    float v = (t >= 0) ? zx[(size_t)(bl + k - 3) * NPAD + 2048 + c] : 0.f;
    acc += v * cw[c*4 + k];
  }
  float s = acc * sigmoidf_(acc);
  u16 sv = f2bf(s);
  if(c < DINNER)            xq[(size_t)bl * DINNER + c] = sv;
  else if(c < DINNER + 128) Bq[(size_t)bl * 128 + (c - DINNER)] = sv;
  else                      Cq[(size_t)bl * 128 + (c - DINNER - 128)] = sv;
}

// ---------------- dt = softplus(dt_raw + dt_bias) ----------------
__global__ __launch_bounds__(256) void k_dt(const float* __restrict__ zx,
                                            const float* __restrict__ dt_bias,
                                            float* __restrict__ dtb){
  size_t i = (size_t)blockIdx.x * 256 + threadIdx.x;
  int h  = (int)(i & 31);
  size_t bl = i >> 5;
  float v = zx[bl * NPAD + 4352 + h] + dt_bias[h];
  dtb[i] = (v > 20.f) ? v : log1pf(expf(v));
}

// ---------------- per-chunk cumsum of a = dt*A ----------------
__global__ __launch_bounds__(256) void k_acum(const float* __restrict__ dtb,
                                              const float* __restrict__ A_log,
                                              float* __restrict__ acum,
                                              float* __restrict__ cdec){
  int bid = blockIdx.x;               // (b*8+c)*32+h
  int h = bid & 31, c = (bid >> 5) & 7, b = bid >> 8;
  int t = threadIdx.x;
  __shared__ float sb[256];
  float Ah = -expf(A_log[h]);
  float a = dtb[(size_t)(b*SEQ + c*CHUNK + t) * 32 + h] * Ah;
  sb[t] = a; __syncthreads();
  for(int off = 1; off < 256; off <<= 1){
    float v = (t >= off) ? sb[t - off] : 0.f;
    __syncthreads();
    sb[t] += v;
    __syncthreads();
  }
  float ac = sb[t];
  acum[(size_t)bid * 256 + t] = ac;
  if(t == 255) cdec[bid] = expf(ac);
}

// ---------------- chunk-final states ----------------
__global__ __launch_bounds__(256) void k_states(const u16* __restrict__ xq, const u16* __restrict__ Bq,
                                                const float* __restrict__ dtb,
                                                const float* __restrict__ acum,
                                                float* __restrict__ states){
  int bid = blockIdx.x;               // (b*8+c)*32+h
  int h = bid & 31, c = (bid >> 5) & 7, b = bid >> 8;
  int tid = threadIdx.x;
  int w = tid >> 6, lane = tid & 63, r = lane & 15, q = lane >> 4;
  __shared__ u16 xT[64*72];           // [p][l] transposed (x*dt)
  __shared__ u16 bT[128*72];          // [n][l] transposed (B*decay)
  size_t rowB = (size_t)(b*SEQ + c*CHUNK);
  float alast = acum[(size_t)bid * 256 + 255];
  f32x4 acc[4][2] = {};
  for(int slab = 0; slab < 4; slab++){
    int lb = slab * 64;
    int l = lane;                                    // one l-row per lane
    float ac  = acum[(size_t)bid * 256 + lb + l];
    float dsl = expf(alast - ac);
    float dtl = dtb[(rowB + lb + l) * 32 + h];
    __syncthreads();     // previous slab's MFMA reads done before overwrite
    {                    // x slab: wave w covers p = w*16 .. w*16+16
      const u16* xp = xq + (rowB + lb + l) * DINNER + h*64 + w*16;
      #pragma unroll
      for(int k = 0; k < 2; k++){
        u16x8 v = *(const u16x8*)(xp + k*8);
        #pragma unroll
        for(int m = 0; m < 8; m++)
          xT[(w*16 + k*8 + m)*72 + l] = f2bf(bf2f(v[m]) * dtl);
      }
    }
    {                    // B slab: wave w covers n = w*32 .. w*32+32
      const u16* bp = Bq + (rowB + lb + l) * 128 + w*32;
      #pragma unroll
      for(int k = 0; k < 4; k++){
        u16x8 v = *(const u16x8*)(bp + k*8);
        #pragma unroll
        for(int m = 0; m < 8; m++)
          bT[(w*32 + k*8 + m)*72 + l] = f2bf(bf2f(v[m]) * dsl);
      }
    }
    __syncthreads();
    #pragma unroll
    for(int ks = 0; ks < 2; ks++){
      bf16x8 af[4], bfr[2];
      #pragma unroll
      for(int i = 0; i < 4; i++) af[i]  = *(const bf16x8*)&xT[(i*16 + r)*72 + ks*32 + q*8];
      #pragma unroll
      for(int j = 0; j < 2; j++) bfr[j] = *(const bf16x8*)&bT[(w*32 + j*16 + r)*72 + ks*32 + q*8];
      #pragma unroll
      for(int i = 0; i < 4; i++)
        #pragma unroll
        for(int j = 0; j < 2; j++)
          acc[i][j] = __builtin_amdgcn_mfma_f32_16x16x32_bf16(af[i], bfr[j], acc[i][j], 0, 0, 0);
    }
  }
  #pragma unroll
  for(int i = 0; i < 4; i++)
    #pragma unroll
    for(int j = 0; j < 2; j++)
      #pragma unroll
      for(int e = 0; e < 4; e++){
        int p = i*16 + q*4 + e;
        int n = w*32 + j*16 + r;
        states[((size_t)bid * 64 + p) * 128 + n] = acc[i][j][e];
      }
}

// ---------------- inter-chunk sequential scan ----------------
__global__ __launch_bounds__(256) void k_scan(const float* __restrict__ states,
                                              const float* __restrict__ cdec,
                                              float* __restrict__ prev){
  size_t i = (size_t)blockIdx.x * 256 + threadIdx.x;
  int n = (int)(i & 127), p = (int)((i >> 7) & 63), h = (int)((i >> 13) & 31), b = (int)(i >> 18);
  float carry = 0.f;
  for(int c = 0; c < NCHUNK; c++){
    int bch = (b*8 + c)*32 + h;
    size_t off = ((size_t)bch * 64 + p) * 128 + n;
    float s = states[off];
    prev[off] = carry;
    carry = carry * cdec[bch] + s;
  }
}

// ---------------- Y = Y_off + Y_diag + D*x ----------------
// one 256-thread block per (b,c,h); wave w handles l-tile w. x^T staged ONCE.
// dt[s] folded into G so xT holds raw x (reused by the D*x epilogue).
// NOTE: no __syncthreads inside the causal st loop (per-wave trip counts differ).
__global__ __launch_bounds__(256) void k_y(const u16* __restrict__ xq, const u16* __restrict__ Bq,
                                           const u16* __restrict__ Cq, const float* __restrict__ dtb,
                                           const float* __restrict__ acum, const float* __restrict__ prev,
                                           const float* __restrict__ D_param, float* __restrict__ out){
  int bch = blockIdx.x;                 // (b*8+c)*32+h
  int h = bch & 31, c = (bch >> 5) & 7, b = bch >> 8;
  int tid = threadIdx.x;
  int w = tid >> 6, lane = tid & 63, r = lane & 15, q = lane >> 4;
  int l0 = w * 64;                      // wave w = l-tile w
  __shared__ float acl[256];
  __shared__ float dts[256];
  __shared__ u16 xT[64*264];            // [p][l] raw x, whole chunk
  __shared__ u16 G[4][64*72];           // per-wave G buffer
  size_t rowC = (size_t)(b*SEQ + c*CHUNK);
  acl[tid] = acum[(size_t)bch * 256 + tid];
  dts[tid] = dtb[(rowC + tid) * 32 + h];
  {                                     // stage x^T: one chunk-row per thread
    const u16* xp = xq + (rowC + tid) * DINNER + h*64;
    #pragma unroll
    for(int k = 0; k < 8; k++){
      u16x8 v = *(const u16x8*)(xp + k*8);
      #pragma unroll
      for(int m = 0; m < 8; m++)
        xT[(k*8 + m)*264 + tid] = v[m];
    }
  }
  __syncthreads();                      // the only block barrier
  // C fragments (reused by Y_off and all s-tiles)
  bf16x8 cf[4][4];
  #pragma unroll
  for(int i = 0; i < 4; i++)
    #pragma unroll
    for(int ks = 0; ks < 4; ks++)
      cf[i][ks] = *(const bf16x8*)&Cq[(rowC + l0 + i*16 + r) * 128 + ks*32 + q*8];
  // Y_off = C . prev^T
  f32x4 accY[4][4] = {};
  #pragma unroll
  for(int ks = 0; ks < 4; ks++){
    #pragma unroll
    for(int j = 0; j < 4; j++){
      const float* pp = prev + ((size_t)bch * 64 + j*16 + r) * 128 + ks*32 + q*8;
      float4 v0 = *(const float4*)pp;
      float4 v1 = *(const float4*)(pp + 4);
      bf16x8 bf;
      bf[0]=(__bf16)v0.x; bf[1]=(__bf16)v0.y; bf[2]=(__bf16)v0.z; bf[3]=(__bf16)v0.w;
      bf[4]=(__bf16)v1.x; bf[5]=(__bf16)v1.y; bf[6]=(__bf16)v1.z; bf[7]=(__bf16)v1.w;
      #pragma unroll
      for(int i = 0; i < 4; i++)
        accY[i][j] = __builtin_amdgcn_mfma_f32_16x16x32_bf16(cf[i][ks], bf, accY[i][j], 0, 0, 0);
    }
  }
  #pragma unroll
  for(int i = 0; i < 4; i++)
    #pragma unroll
    for(int e = 0; e < 4; e++){
      float sc = expf(acl[l0 + i*16 + q*4 + e]);
      #pragma unroll
      for(int j = 0; j < 4; j++) accY[i][j][e] *= sc;
    }
  // diagonal blocks: S = C.B^T; G = mask.decay(S)*dt; Y += G.x^T
  u16* Gw = G[w];
  for(int st = 0; st <= w; st++){
    int s0 = st * 64;
    f32x4 accS[4][4] = {};
    #pragma unroll
    for(int ks = 0; ks < 4; ks++){
      #pragma unroll
      for(int j = 0; j < 4; j++){
        bf16x8 bfr = *(const bf16x8*)&Bq[(rowC + s0 + j*16 + r) * 128 + ks*32 + q*8];
        #pragma unroll
        for(int i = 0; i < 4; i++)
          accS[i][j] = __builtin_amdgcn_mfma_f32_16x16x32_bf16(cf[i][ks], bfr, accS[i][j], 0, 0, 0);
      }
    }
    #pragma unroll
    for(int i = 0; i < 4; i++)
      #pragma unroll
      for(int j = 0; j < 4; j++)
        #pragma unroll
        for(int e = 0; e < 4; e++){
          int ll = l0 + i*16 + q*4 + e;
          int ss = s0 + j*16 + r;
          float v = (ll >= ss) ? accS[i][j][e] * expf(acl[ll] - acl[ss]) * dts[ss] : 0.f;
          Gw[(i*16 + q*4 + e)*72 + j*16 + r] = f2bf(v);
        }
    #pragma unroll
    for(int ks = 0; ks < 2; ks++){
      bf16x8 gf[4], xf[4];
      #pragma unroll
      for(int i = 0; i < 4; i++) gf[i] = *(const bf16x8*)&Gw[(i*16 + r)*72 + ks*32 + q*8];
      #pragma unroll
      for(int j = 0; j < 4; j++) xf[j] = *(const bf16x8*)&xT[(j*16 + r)*264 + s0 + ks*32 + q*8];
      #pragma unroll
      for(int i = 0; i < 4; i++)
        #pragma unroll
        for(int j = 0; j < 4; j++)
          accY[i][j] = __builtin_amdgcn_mfma_f32_16x16x32_bf16(gf[i], xf[j], accY[i][j], 0, 0, 0);
    }
  }
  // epilogue: + D*x (x read back from LDS), write Y
  float Dh = D_param[h];
  #pragma unroll
  for(int i = 0; i < 4; i++)
    #pragma unroll
    for(int j = 0; j < 4; j++)
      #pragma unroll
      for(int e = 0; e < 4; e++){
        int ll = l0 + i*16 + q*4 + e;
        int p = j*16 + r;
        float xv = bf2f(xT[p*264 + ll]);
        out[(rowC + ll) * (size_t)DINNER + h*64 + p] = accY[i][j][e] + Dh * xv;
      }
}

// ---------------- gated RMSNorm ----------------
__global__ __launch_bounds__(256) void k_norm(float* __restrict__ out, const float* __restrict__ zx,
                                              const float* __restrict__ nw){
  int bl = blockIdx.x;
  int t = threadIdx.x;
  float g[8];
  float ss = 0.f;
  #pragma unroll
  for(int it = 0; it < 8; it++){
    int cidx = it*256 + t;
    float y = out[(size_t)bl * DINNER + cidx];
    float z = zx[(size_t)bl * NPAD + cidx];
    float v = y * (z * sigmoidf_(z));
    g[it] = v;
    ss += v * v;
  }
  #pragma unroll
  for(int off = 32; off > 0; off >>= 1) ss += __shfl_down(ss, off, 64);
  __shared__ float wsum[4];
  if((t & 63) == 0) wsum[t >> 6] = ss;
  __syncthreads();
  float tot = wsum[0] + wsum[1] + wsum[2] + wsum[3];
  float scale = rsqrtf(tot / (float)DINNER + EPS);
  #pragma unroll
  for(int it = 0; it < 8; it++){
    int cidx = it*256 + t;
    out[(size_t)bl * DINNER + cidx] = g[it] * scale * nw[cidx];
  }
}

extern "C" void kernel_launch(void* const* d_in, const int* in_sizes, int n_in,
                              void* d_out, int out_size, void* d_ws, size_t ws_size,
                              hipStream_t stream){
  const float* u    = (const float*)d_in[0];
  const float* W    = (const float*)d_in[1];
  const float* cw   = (const float*)d_in[2];
  const float* cb   = (const float*)d_in[3];
  const float* dtbi = (const float*)d_in[4];
  const float* Alog = (const float*)d_in[5];
  const float* Dp   = (const float*)d_in[6];
  const float* nw   = (const float*)d_in[7];
  float* out = (float*)d_out;

  char* ws = (char*)d_ws;
  size_t off = 0;
  auto alloc = [&](size_t bytes) -> void* {
    void* p = ws + off;
    off += (bytes + 255) & ~(size_t)255;
    return p;
  };
  u16*   u_bf    = (u16*)  alloc((size_t)MROWS * KDIM * 2);
  u16*   W_bf    = (u16*)  alloc((size_t)NPAD * KDIM * 2);
  float* zxbcdt  = (float*)alloc((size_t)MROWS * NPAD * 4);
  u16*   xq      = (u16*)  alloc((size_t)MROWS * DINNER * 2);
  u16*   Bq      = (u16*)  alloc((size_t)MROWS * 128 * 2);
  u16*   Cq      = (u16*)  alloc((size_t)MROWS * 128 * 2);
  float* dtb     = (float*)alloc((size_t)MROWS * 32 * 4);
  float* acum    = (float*)alloc((size_t)512 * 256 * 4);
  float* cdec    = (float*)alloc((size_t)512 * 4);
  float* states  = (float*)alloc((size_t)512 * 64 * 128 * 4);
  float* prev    = (float*)alloc((size_t)512 * 64 * 128 * 4);

  k_cvt_u<<<(MROWS*KDIM)/(256*4), 256, 0, stream>>>(u, u_bf);
  k_cvt_w<<<((size_t)NPAD*KDIM)/(256*4), 256, 0, stream>>>(W, W_bf);
  k_gemm<<<dim3(NPAD/128, MROWS/128), 256, 0, stream>>>(u_bf, W_bf, zxbcdt);
  k_conv<<<((size_t)MROWS*CONVDIM)/256, 256, 0, stream>>>(zxbcdt, cw, cb, xq, Bq, Cq);
  k_dt<<<((size_t)MROWS*32)/256, 256, 0, stream>>>(zxbcdt, dtbi, dtb);
  k_acum<<<512, 256, 0, stream>>>(dtb, Alog, acum, cdec);
  k_states<<<512, 256, 0, stream>>>(xq, Bq, dtb, acum, states);
  k_scan<<<((size_t)BATCH*NHEADS*64*128)/256, 256, 0, stream>>>(states, cdec, prev);
  k_y<<<512, 256, 0, stream>>>(xq, Bq, Cq, dtb, acum, prev, Dp, out);
  k_norm<<<MROWS, 256, 0, stream>>>(out, zxbcdt, nw);
}

// Round 3
// 305.319 us; speedup vs baseline: 1.1811x; 1.0729x over previous
//
#include <hip/hip_runtime.h>
#include <cstdint>
#include <cmath>

#define KDIM    1024
#define DPROJ   4384
#define NPAD    4480   // 4384 padded to 35*128
#define CONVDIM 2304
#define SEQ     2048
#define BATCH   2
#define MROWS   4096   // BATCH*SEQ
#define NHEADS  32
#define HEADDIM 64
#define DSTATE  128
#define CHUNK   256
#define NCHUNK  8
#define DINNER  2048
#define EPS     1e-5f

typedef unsigned short u16;
typedef float  f32x4  __attribute__((ext_vector_type(4)));
typedef __bf16 bf16x8 __attribute__((ext_vector_type(8)));
typedef u16    u16x8  __attribute__((ext_vector_type(8)));

__device__ __forceinline__ u16 f2bf(float f){
  unsigned u = __builtin_bit_cast(unsigned, f);
  u += 0x7fffu + ((u >> 16) & 1u);   // RNE
  return (u16)(u >> 16);
}
__device__ __forceinline__ float bf2f(u16 s){
  unsigned u = ((unsigned)s) << 16;
  return __builtin_bit_cast(float, u);
}
__device__ __forceinline__ void gl_lds16(const void* g, void* l){
  __builtin_amdgcn_global_load_lds((const __attribute__((address_space(1))) void*)g,
                                   (__attribute__((address_space(3))) void*)l, 16, 0, 0);
}
__device__ __forceinline__ float sigmoidf_(float x){ return 1.f / (1.f + expf(-x)); }

// ---------------- fp32 -> bf16 conversion (u and W merged) ----------------
__global__ __launch_bounds__(256) void k_cvt(const float* __restrict__ u_in, u16* __restrict__ u_out,
                                             const float* __restrict__ w_in, u16* __restrict__ w_out){
  int bid = blockIdx.x;
  const float* in; u16* out; size_t i; int wpath = 0;
  if(bid < 4096){ in = u_in; out = u_out; i = ((size_t)bid * 256 + threadIdx.x) * 4; }
  else          { in = w_in; out = w_out; i = ((size_t)(bid - 4096) * 256 + threadIdx.x) * 4; wpath = 1; }
  float4 v = make_float4(0.f,0.f,0.f,0.f);
  if(!wpath || (int)(i >> 10) < DPROJ) v = *(const float4*)(in + i);
  unsigned a = (unsigned)f2bf(v.x) | ((unsigned)f2bf(v.y) << 16);
  unsigned b = (unsigned)f2bf(v.z) | ((unsigned)f2bf(v.w) << 16);
  uint2 o; o.x = a; o.y = b;
  *(uint2*)(out + i) = o;
}

// ---------------- in-projection GEMM: zq = bf16(u @ W^T), dt cols also fp32 ----------------
__global__ __launch_bounds__(256) void k_gemm(const u16* __restrict__ A, const u16* __restrict__ B,
                                              u16* __restrict__ zq, float* __restrict__ dtraw){
  __shared__ u16 As[128*32];
  __shared__ u16 Bs[128*32];
  int tid = threadIdx.x;
  // swizzle: bands of 8 m-tiles sweep n together (L2 locality)
  int gid = blockIdx.x;
  int mG  = gid / (35*8);
  int rem = gid % (35*8);
  int nblk = rem / 8;
  int mblk = mG*8 + (rem & 7);
  int m0 = mblk * 128, n0 = nblk * 128;
  int w = tid >> 6, lane = tid & 63, r = lane & 15, q = lane >> 4;
  int wm = (w >> 1) * 64, wn = (w & 1) * 64;
  f32x4 acc[4][4] = {};
  const u16* Ag0 = A + (size_t)(m0 +       (tid >> 2)) * KDIM + (tid & 3) * 8;
  const u16* Ag1 = A + (size_t)(m0 + 64 +  (tid >> 2)) * KDIM + (tid & 3) * 8;
  const u16* Bg0 = B + (size_t)(n0 +       (tid >> 2)) * KDIM + (tid & 3) * 8;
  const u16* Bg1 = B + (size_t)(n0 + 64 +  (tid >> 2)) * KDIM + (tid & 3) * 8;
  for(int kt = 0; kt < KDIM/32; kt++){
    int k0 = kt * 32;
    gl_lds16(Ag0 + k0, &As[(size_t)tid * 8]);
    gl_lds16(Ag1 + k0, &As[((size_t)tid + 256) * 8]);
    gl_lds16(Bg0 + k0, &Bs[(size_t)tid * 8]);
    gl_lds16(Bg1 + k0, &Bs[((size_t)tid + 256) * 8]);
    __syncthreads();
    bf16x8 af[4], bfm[4];
    #pragma unroll
    for(int i = 0; i < 4; i++) af[i]  = *(const bf16x8*)&As[(wm + i*16 + r) * 32 + q*8];
    #pragma unroll
    for(int j = 0; j < 4; j++) bfm[j] = *(const bf16x8*)&Bs[(wn + j*16 + r) * 32 + q*8];
    #pragma unroll
    for(int i = 0; i < 4; i++)
      #pragma unroll
      for(int j = 0; j < 4; j++)
        acc[i][j] = __builtin_amdgcn_mfma_f32_16x16x32_bf16(af[i], bfm[j], acc[i][j], 0, 0, 0);
    __syncthreads();
  }
  #pragma unroll
  for(int i = 0; i < 4; i++)
    #pragma unroll
    for(int j = 0; j < 4; j++)
      #pragma unroll
      for(int e = 0; e < 4; e++){
        int row = m0 + wm + i*16 + q*4 + e;
        int col = n0 + wn + j*16 + r;
        zq[(size_t)row * NPAD + col] = f2bf(acc[i][j][e]);
        if(nblk == 34) dtraw[(size_t)row * 128 + (col - 4352)] = acc[i][j][e];
      }
}

// ---------------- conv1d + silu + split, emits xq (row-major) AND xqT (head-transposed) ----------------
__global__ __launch_bounds__(256) void k_conv(const u16* __restrict__ zq,
                                              const float* __restrict__ cw,
                                              const float* __restrict__ cb,
                                              u16* __restrict__ xq, u16* __restrict__ xqT,
                                              u16* __restrict__ Bq, u16* __restrict__ Cq){
  int c0 = blockIdx.x * 64;             // 36 c-tiles over CONVDIM
  int l0 = blockIdx.y * 64;             // 32 l-tiles over SEQ
  int b  = blockIdx.z;
  int lane = threadIdx.x & 63;
  int c = c0 + lane;
  int lb = l0 + (threadIdx.x >> 6) * 16;
  float wt0 = cw[c*4+0], wt1 = cw[c*4+1], wt2 = cw[c*4+2], wt3 = cw[c*4+3];
  float bias = cb[c];
  const u16* zrow = zq + (size_t)(b*SEQ) * NPAD + 2048 + c;
  float w0 = (lb-3 >= 0) ? bf2f(zrow[(size_t)(lb-3)*NPAD]) : 0.f;
  float w1 = (lb-2 >= 0) ? bf2f(zrow[(size_t)(lb-2)*NPAD]) : 0.f;
  float w2 = (lb-1 >= 0) ? bf2f(zrow[(size_t)(lb-1)*NPAD]) : 0.f;
  u16 vals[16];
  #pragma unroll
  for(int rr = 0; rr < 16; rr++){
    float in3 = bf2f(zrow[(size_t)(lb+rr)*NPAD]);
    float a = bias + w0*wt0 + w1*wt1 + w2*wt2 + in3*wt3;
    vals[rr] = f2bf(a * sigmoidf_(a));
    w0 = w1; w1 = w2; w2 = in3;
  }
  if(blockIdx.x < 32){                  // x region
    #pragma unroll
    for(int rr = 0; rr < 16; rr++)
      xq[(size_t)(b*SEQ + lb + rr) * DINNER + c] = vals[rr];
    int h = c0 >> 6;
    u16* dst = xqT + ((size_t)((b*32 + h)*64) + lane) * SEQ + lb;
    u16x8 v0, v1;
    #pragma unroll
    for(int m = 0; m < 8; m++){ v0[m] = vals[m]; v1[m] = vals[8+m]; }
    *(u16x8*)dst = v0;
    *(u16x8*)(dst + 8) = v1;
  } else {
    u16* dst; int col;
    if(blockIdx.x < 34){ dst = Bq; col = c0 - 2048 + lane; }
    else               { dst = Cq; col = c0 - 2176 + lane; }
    #pragma unroll
    for(int rr = 0; rr < 16; rr++)
      dst[(size_t)(b*SEQ + lb + rr) * 128 + col] = vals[rr];
  }
}

// ---------------- dt=softplus(dtraw+bias) + per-chunk cumsum of dt*A ----------------
__global__ __launch_bounds__(256) void k_acum(const float* __restrict__ dtraw,
                                              const float* __restrict__ dt_bias,
                                              const float* __restrict__ A_log,
                                              float* __restrict__ dtb,
                                              float* __restrict__ acum,
                                              float* __restrict__ cdec){
  int bid = blockIdx.x;               // (b*8+c)*32+h
  int h = bid & 31, c = (bid >> 5) & 7, b = bid >> 8;
  int t = threadIdx.x;
  __shared__ float sb[256];
  size_t row = (size_t)(b*SEQ + c*CHUNK + t);
  float v = dtraw[row * 128 + h] + dt_bias[h];
  float dt = (v > 20.f) ? v : log1pf(expf(v));
  dtb[row * 32 + h] = dt;
  float Ah = -expf(A_log[h]);
  float a = dt * Ah;
  sb[t] = a; __syncthreads();
  for(int off = 1; off < 256; off <<= 1){
    float vv = (t >= off) ? sb[t - off] : 0.f;
    __syncthreads();
    sb[t] += vv;
    __syncthreads();
  }
  float ac = sb[t];
  acum[(size_t)bid * 256 + t] = ac;
  if(t == 255) cdec[bid] = expf(ac);
}

// ---------------- chunk-final states: x^T from global, decay*dt folded into B ----------------
__global__ __launch_bounds__(256) void k_states(const u16* __restrict__ xqT, const u16* __restrict__ Bq,
                                                const float* __restrict__ dtb,
                                                const float* __restrict__ acum,
                                                float* __restrict__ states){
  int bid = blockIdx.x;               // (b*8+c)*32+h
  int h = bid & 31, c = (bid >> 5) & 7, b = bid >> 8;
  int tid = threadIdx.x;
  int w = tid >> 6, lane = tid & 63, r = lane & 15, q = lane >> 4;
  __shared__ u16 bT[128*72];          // [n][l], B * exp(alast-acum) * dt
  size_t rowB = (size_t)(b*SEQ + c*CHUNK);
  const u16* xrow = xqT + (size_t)((b*32 + h)*64) * SEQ + c*CHUNK;
  float alast = acum[(size_t)bid * 256 + 255];
  f32x4 acc[4][2] = {};
  for(int slab = 0; slab < 4; slab++){
    int lb = slab * 64;
    int l = lane;
    float f = expf(alast - acum[(size_t)bid * 256 + lb + l]) * dtb[(rowB + lb + l) * 32 + h];
    __syncthreads();
    const u16* bp = Bq + (rowB + lb + l) * 128 + w*32;
    #pragma unroll
    for(int k = 0; k < 4; k++){
      u16x8 v = *(const u16x8*)(bp + k*8);
      #pragma unroll
      for(int m = 0; m < 8; m++)
        bT[(w*32 + k*8 + m)*72 + l] = f2bf(bf2f(v[m]) * f);
    }
    __syncthreads();
    #pragma unroll
    for(int ks = 0; ks < 2; ks++){
      bf16x8 af[4], bfr[2];
      #pragma unroll
      for(int i = 0; i < 4; i++)
        af[i] = *(const bf16x8*)&xrow[(size_t)(i*16 + r) * SEQ + lb + ks*32 + q*8];
      #pragma unroll
      for(int j = 0; j < 2; j++) bfr[j] = *(const bf16x8*)&bT[(w*32 + j*16 + r)*72 + ks*32 + q*8];
      #pragma unroll
      for(int i = 0; i < 4; i++)
        #pragma unroll
        for(int j = 0; j < 2; j++)
          acc[i][j] = __builtin_amdgcn_mfma_f32_16x16x32_bf16(af[i], bfr[j], acc[i][j], 0, 0, 0);
    }
  }
  #pragma unroll
  for(int i = 0; i < 4; i++)
    #pragma unroll
    for(int j = 0; j < 2; j++)
      #pragma unroll
      for(int e = 0; e < 4; e++){
        int p = i*16 + q*4 + e;
        int n = w*32 + j*16 + r;
        states[((size_t)bid * 64 + p) * 128 + n] = acc[i][j][e];
      }
}

// ---------------- inter-chunk sequential scan (prev emitted bf16) ----------------
__global__ __launch_bounds__(256) void k_scan(const float* __restrict__ states,
                                              const float* __restrict__ cdec,
                                              u16* __restrict__ prevb){
  size_t i = (size_t)blockIdx.x * 256 + threadIdx.x;
  int n = (int)(i & 127), p = (int)((i >> 7) & 63), h = (int)((i >> 13) & 31), b = (int)(i >> 18);
  float carry = 0.f;
  for(int c = 0; c < NCHUNK; c++){
    int bch = (b*8 + c)*32 + h;
    size_t off = ((size_t)bch * 64 + p) * 128 + n;
    float s = states[off];
    prevb[off] = f2bf(carry);
    carry = carry * cdec[bch] + s;
  }
}

// ---------------- Y = Y_off + Y_diag (bf16 out); balanced l-tile pairs {0,3},{1,2} ----------------
__global__ __launch_bounds__(128) void k_y(const u16* __restrict__ xqT, const u16* __restrict__ Bq,
                                           const u16* __restrict__ Cq, const float* __restrict__ dtb,
                                           const float* __restrict__ acum, const u16* __restrict__ prevb,
                                           u16* __restrict__ yq){
  int bid = blockIdx.x;                 // bch*2 + pair
  int bch = bid >> 1, pr = bid & 1;
  int h = bch & 31, c = (bch >> 5) & 7, b = bch >> 8;
  int tid = threadIdx.x;
  int w2 = tid >> 6, lane = tid & 63, r = lane & 15, q = lane >> 4;
  int lt = pr ? (1 + w2) : (w2 * 3);    // pair0: {0,3}, pair1: {1,2}
  int l0 = lt * 64;
  __shared__ float acl[256];
  __shared__ float dts[256];
  __shared__ u16 G[2][64*72];
  size_t rowC = (size_t)(b*SEQ + c*CHUNK);
  #pragma unroll
  for(int it = 0; it < 2; it++){
    int s = it*128 + tid;
    acl[s] = acum[(size_t)bch * 256 + s];
    dts[s] = dtb[(rowC + s) * 32 + h];
  }
  __syncthreads();                      // only block barrier
  // C fragments
  bf16x8 cf[4][4];
  #pragma unroll
  for(int i = 0; i < 4; i++)
    #pragma unroll
    for(int ks = 0; ks < 4; ks++)
      cf[i][ks] = *(const bf16x8*)&Cq[(rowC + l0 + i*16 + r) * 128 + ks*32 + q*8];
  // Y_off = C . prev^T  (prev bf16, fragment-ready)
  f32x4 accY[4][4] = {};
  #pragma unroll
  for(int ks = 0; ks < 4; ks++){
    #pragma unroll
    for(int j = 0; j < 4; j++){
      bf16x8 bfr = *(const bf16x8*)&prevb[((size_t)bch * 64 + j*16 + r) * 128 + ks*32 + q*8];
      #pragma unroll
      for(int i = 0; i < 4; i++)
        accY[i][j] = __builtin_amdgcn_mfma_f32_16x16x32_bf16(cf[i][ks], bfr, accY[i][j], 0, 0, 0);
    }
  }
  #pragma unroll
  for(int i = 0; i < 4; i++)
    #pragma unroll
    for(int e = 0; e < 4; e++){
      float sc = expf(acl[l0 + i*16 + q*4 + e]);
      #pragma unroll
      for(int j = 0; j < 4; j++) accY[i][j][e] *= sc;
    }
  // diagonal blocks
  const u16* xrow = xqT + (size_t)((b*32 + h)*64) * SEQ + c*CHUNK;
  u16* Gw = G[w2];
  for(int st = 0; st <= lt; st++){
    int s0 = st * 64;
    f32x4 accS[4][4] = {};
    #pragma unroll
    for(int ks = 0; ks < 4; ks++){
      #pragma unroll
      for(int j = 0; j < 4; j++){
        bf16x8 bfr = *(const bf16x8*)&Bq[(rowC + s0 + j*16 + r) * 128 + ks*32 + q*8];
        #pragma unroll
        for(int i = 0; i < 4; i++)
          accS[i][j] = __builtin_amdgcn_mfma_f32_16x16x32_bf16(cf[i][ks], bfr, accS[i][j], 0, 0, 0);
      }
    }
    #pragma unroll
    for(int i = 0; i < 4; i++)
      #pragma unroll
      for(int j = 0; j < 4; j++)
        #pragma unroll
        for(int e = 0; e < 4; e++){
          int ll = l0 + i*16 + q*4 + e;
          int ss = s0 + j*16 + r;
          float v = (ll >= ss) ? accS[i][j][e] * expf(acl[ll] - acl[ss]) * dts[ss] : 0.f;
          Gw[(i*16 + q*4 + e)*72 + j*16 + r] = f2bf(v);
        }
    #pragma unroll
    for(int ks = 0; ks < 2; ks++){
      bf16x8 gf[4], xf[4];
      #pragma unroll
      for(int i = 0; i < 4; i++) gf[i] = *(const bf16x8*)&Gw[(i*16 + r)*72 + ks*32 + q*8];
      #pragma unroll
      for(int j = 0; j < 4; j++)
        xf[j] = *(const bf16x8*)&xrow[(size_t)(j*16 + r) * SEQ + s0 + ks*32 + q*8];
      #pragma unroll
      for(int i = 0; i < 4; i++)
        #pragma unroll
        for(int j = 0; j < 4; j++)
          accY[i][j] = __builtin_amdgcn_mfma_f32_16x16x32_bf16(gf[i], xf[j], accY[i][j], 0, 0, 0);
    }
  }
  #pragma unroll
  for(int i = 0; i < 4; i++)
    #pragma unroll
    for(int j = 0; j < 4; j++)
      #pragma unroll
      for(int e = 0; e < 4; e++){
        int ll = l0 + i*16 + q*4 + e;
        int p = j*16 + r;
        yq[(rowC + ll) * (size_t)DINNER + h*64 + p] = f2bf(accY[i][j][e]);
      }
}

// ---------------- gated RMSNorm + D*x fold, fp32 output ----------------
__global__ __launch_bounds__(256) void k_norm(const u16* __restrict__ yq, const u16* __restrict__ xq,
                                              const u16* __restrict__ zq, const float* __restrict__ Dp,
                                              const float* __restrict__ nw, float* __restrict__ out){
  int bl = blockIdx.x;
  int t = threadIdx.x;
  float Dh = Dp[t >> 3];                 // 8 cols per thread, 64 cols per head
  u16x8 yv = *(const u16x8*)(yq + (size_t)bl * DINNER + t*8);
  u16x8 xv = *(const u16x8*)(xq + (size_t)bl * DINNER + t*8);
  u16x8 zv = *(const u16x8*)(zq + (size_t)bl * NPAD + t*8);
  float g[8];
  float ss = 0.f;
  #pragma unroll
  for(int m = 0; m < 8; m++){
    float y = bf2f(yv[m]) + Dh * bf2f(xv[m]);
    float z = bf2f(zv[m]);
    float v = y * (z * sigmoidf_(z));
    g[m] = v;
    ss += v * v;
  }
  #pragma unroll
  for(int off = 32; off > 0; off >>= 1) ss += __shfl_down(ss, off, 64);
  __shared__ float wsum[4];
  if((t & 63) == 0) wsum[t >> 6] = ss;
  __syncthreads();
  float tot = wsum[0] + wsum[1] + wsum[2] + wsum[3];
  float scale = rsqrtf(tot / (float)DINNER + EPS);
  float4 o0, o1;
  o0.x = g[0]*scale*nw[t*8+0]; o0.y = g[1]*scale*nw[t*8+1];
  o0.z = g[2]*scale*nw[t*8+2]; o0.w = g[3]*scale*nw[t*8+3];
  o1.x = g[4]*scale*nw[t*8+4]; o1.y = g[5]*scale*nw[t*8+5];
  o1.z = g[6]*scale*nw[t*8+6]; o1.w = g[7]*scale*nw[t*8+7];
  *(float4*)(out + (size_t)bl * DINNER + t*8)     = o0;
  *(float4*)(out + (size_t)bl * DINNER + t*8 + 4) = o1;
}

extern "C" void kernel_launch(void* const* d_in, const int* in_sizes, int n_in,
                              void* d_out, int out_size, void* d_ws, size_t ws_size,
                              hipStream_t stream){
  const float* u    = (const float*)d_in[0];
  const float* W    = (const float*)d_in[1];
  const float* cw   = (const float*)d_in[2];
  const float* cb   = (const float*)d_in[3];
  const float* dtbi = (const float*)d_in[4];
  const float* Alog = (const float*)d_in[5];
  const float* Dp   = (const float*)d_in[6];
  const float* nw   = (const float*)d_in[7];
  float* out = (float*)d_out;

  char* ws = (char*)d_ws;
  size_t off = 0;
  auto alloc = [&](size_t bytes) -> void* {
    void* p = ws + off;
    off += (bytes + 255) & ~(size_t)255;
    return p;
  };
  u16*   u_bf    = (u16*)  alloc((size_t)MROWS * KDIM * 2);        //  8.4 MB
  u16*   W_bf    = (u16*)  alloc((size_t)NPAD * KDIM * 2);         //  9.2 MB
  u16*   zq      = (u16*)  alloc((size_t)MROWS * NPAD * 2);        // 36.7 MB
  float* dtraw   = (float*)alloc((size_t)MROWS * 128 * 4);         //  2.1 MB
  u16*   xq      = (u16*)  alloc((size_t)MROWS * DINNER * 2);      // 16.8 MB
  u16*   xqT     = (u16*)  alloc((size_t)MROWS * DINNER * 2);      // 16.8 MB
  u16*   Bq      = (u16*)  alloc((size_t)MROWS * 128 * 2);         //  1.0 MB
  u16*   Cq      = (u16*)  alloc((size_t)MROWS * 128 * 2);         //  1.0 MB
  float* dtb     = (float*)alloc((size_t)MROWS * 32 * 4);          //  0.5 MB
  float* acum    = (float*)alloc((size_t)512 * 256 * 4);           //  0.5 MB
  float* cdec    = (float*)alloc((size_t)512 * 4);
  float* states  = (float*)alloc((size_t)512 * 64 * 128 * 4);      // 16.8 MB
  u16*   prevb   = (u16*)  alloc((size_t)512 * 64 * 128 * 2);      //  8.4 MB
  u16*   yq      = (u16*)  alloc((size_t)MROWS * DINNER * 2);      // 16.8 MB

  k_cvt<<<4096 + 4480, 256, 0, stream>>>(u, u_bf, W, W_bf);
  k_gemm<<<35*32, 256, 0, stream>>>(u_bf, W_bf, zq, dtraw);
  k_conv<<<dim3(36, 32, 2), 256, 0, stream>>>(zq, cw, cb, xq, xqT, Bq, Cq);
  k_acum<<<512, 256, 0, stream>>>(dtraw, dtbi, Alog, dtb, acum, cdec);
  k_states<<<512, 256, 0, stream>>>(xqT, Bq, dtb, acum, states);
  k_scan<<<((size_t)BATCH*NHEADS*64*128)/256, 256, 0, stream>>>(states, cdec, prevb);
  k_y<<<1024, 128, 0, stream>>>(xqT, Bq, Cq, dtb, acum, prevb, yq);
  k_norm<<<MROWS, 256, 0, stream>>>(yq, xq, zq, Dp, nw, out);
}

// Round 5
// 304.085 us; speedup vs baseline: 1.1859x; 1.0041x over previous
//
#include <hip/hip_runtime.h>
#include <cstdint>
#include <cmath>

#define KDIM    1024
#define DPROJ   4384
#define NPAD    4480   // 4384 padded to 35*128
#define CONVDIM 2304
#define SEQ     2048
#define BATCH   2
#define MROWS   4096   // BATCH*SEQ
#define NHEADS  32
#define HEADDIM 64
#define DSTATE  128
#define CHUNK   256
#define NCHUNK  8
#define DINNER  2048
#define EPS     1e-5f

typedef unsigned short u16;
typedef float  f32x4  __attribute__((ext_vector_type(4)));
typedef __bf16 bf16x8 __attribute__((ext_vector_type(8)));
typedef u16    u16x8  __attribute__((ext_vector_type(8)));
typedef u16    u16x4  __attribute__((ext_vector_type(4)));

__device__ __forceinline__ u16 f2bf(float f){
  unsigned u = __builtin_bit_cast(unsigned, f);
  u += 0x7fffu + ((u >> 16) & 1u);   // RNE
  return (u16)(u >> 16);
}
__device__ __forceinline__ float bf2f(u16 s){
  unsigned u = ((unsigned)s) << 16;
  return __builtin_bit_cast(float, u);
}
__device__ __forceinline__ void gl_lds16(const void* g, void* l){
  __builtin_amdgcn_global_load_lds((const __attribute__((address_space(1))) void*)g,
                                   (__attribute__((address_space(3))) void*)l, 16, 0, 0);
}
__device__ __forceinline__ float sigmoidf_(float x){ return 1.f / (1.f + expf(-x)); }

// ---------------- fp32 -> bf16 conversion (u and W merged) ----------------
__global__ __launch_bounds__(256) void k_cvt(const float* __restrict__ u_in, u16* __restrict__ u_out,
                                             const float* __restrict__ w_in, u16* __restrict__ w_out){
  int bid = blockIdx.x;
  const float* in; u16* out; size_t i; int wpath = 0;
  if(bid < 4096){ in = u_in; out = u_out; i = ((size_t)bid * 256 + threadIdx.x) * 4; }
  else          { in = w_in; out = w_out; i = ((size_t)(bid - 4096) * 256 + threadIdx.x) * 4; wpath = 1; }
  float4 v = make_float4(0.f,0.f,0.f,0.f);
  if(!wpath || (int)(i >> 10) < DPROJ) v = *(const float4*)(in + i);
  unsigned a = (unsigned)f2bf(v.x) | ((unsigned)f2bf(v.y) << 16);
  unsigned b = (unsigned)f2bf(v.z) | ((unsigned)f2bf(v.w) << 16);
  uint2 o; o.x = a; o.y = b;
  *(uint2*)(out + i) = o;
}

// ---------------- in-projection GEMM: zq = bf16(u @ W^T), BK=64 ----------------
__global__ __launch_bounds__(256) void k_gemm(const u16* __restrict__ A, const u16* __restrict__ B,
                                              u16* __restrict__ zq, float* __restrict__ dtraw){
  __shared__ u16 As[128*64];
  __shared__ u16 Bs[128*64];
  int tid = threadIdx.x;
  // swizzle: bands of 8 m-tiles sweep n together (L2 locality)
  int gid = blockIdx.x;
  int mG  = gid / (35*8);
  int rem = gid % (35*8);
  int nblk = rem / 8;
  int mblk = mG*8 + (rem & 7);
  int m0 = mblk * 128, n0 = nblk * 128;
  int w = tid >> 6, lane = tid & 63, r = lane & 15, q = lane >> 4;
  int wm = (w >> 1) * 64, wn = (w & 1) * 64;
  f32x4 acc[4][4] = {};
  // row within tile = m*32 + (tid>>3), col = (tid&7)*8
  // LDS offset = (m*32 + (tid>>3))*64 + (tid&7)*8 = (m*256 + tid)*8
  const u16* Ag = A + (size_t)(m0 + (tid >> 3)) * KDIM + (tid & 7) * 8;
  const u16* Bg = B + (size_t)(n0 + (tid >> 3)) * KDIM + (tid & 7) * 8;
  for(int kt = 0; kt < KDIM/64; kt++){
    int k0 = kt * 64;
    #pragma unroll
    for(int m = 0; m < 4; m++){
      gl_lds16(Ag + (size_t)m*32*KDIM + k0, &As[((size_t)m*256 + tid) * 8]);
      gl_lds16(Bg + (size_t)m*32*KDIM + k0, &Bs[((size_t)m*256 + tid) * 8]);
    }
    __syncthreads();
    #pragma unroll
    for(int ks = 0; ks < 2; ks++){
      bf16x8 af[4], bfm[4];
      #pragma unroll
      for(int i = 0; i < 4; i++) af[i]  = *(const bf16x8*)&As[(wm + i*16 + r) * 64 + ks*32 + q*8];
      #pragma unroll
      for(int j = 0; j < 4; j++) bfm[j] = *(const bf16x8*)&Bs[(wn + j*16 + r) * 64 + ks*32 + q*8];
      #pragma unroll
      for(int i = 0; i < 4; i++)
        #pragma unroll
        for(int j = 0; j < 4; j++)
          acc[i][j] = __builtin_amdgcn_mfma_f32_16x16x32_bf16(af[i], bfm[j], acc[i][j], 0, 0, 0);
    }
    __syncthreads();
  }
  #pragma unroll
  for(int i = 0; i < 4; i++)
    #pragma unroll
    for(int j = 0; j < 4; j++)
      #pragma unroll
      for(int e = 0; e < 4; e++){
        int row = m0 + wm + i*16 + q*4 + e;
        int col = n0 + wn + j*16 + r;
        zq[(size_t)row * NPAD + col] = f2bf(acc[i][j][e]);
        if(nblk == 34) dtraw[(size_t)row * 128 + (col - 4352)] = acc[i][j][e];
      }
}

// ---------------- conv1d + silu + split; 4 consecutive c per thread (coalesced) ----------------
__global__ __launch_bounds__(256) void k_conv(const u16* __restrict__ zq,
                                              const float* __restrict__ cw,
                                              const float* __restrict__ cb,
                                              u16* __restrict__ xq, u16* __restrict__ xqT,
                                              u16* __restrict__ Bq, u16* __restrict__ Cq){
  int c0 = blockIdx.x * 256;            // 9 c-tiles over CONVDIM (tile 8 == B|C)
  int l0 = blockIdx.y * 64;             // 32 l-tiles over SEQ
  int b  = blockIdx.z;
  int tid = threadIdx.x;
  int cbase = c0 + (tid & 63) * 4;      // 4 consecutive channels
  int lb = l0 + (tid >> 6) * 16;        // 16 rows
  float wt[4][4], bias[4];
  #pragma unroll
  for(int cc = 0; cc < 4; cc++){
    float4 wv = *(const float4*)(cw + (cbase + cc)*4);
    wt[cc][0]=wv.x; wt[cc][1]=wv.y; wt[cc][2]=wv.z; wt[cc][3]=wv.w;
    bias[cc] = cb[cbase + cc];
  }
  const u16* zrow = zq + (size_t)(b*SEQ) * NPAD + 2048 + cbase;
  float w0[4] = {}, w1[4] = {}, w2[4] = {};
  if(lb-3 >= 0){ u16x4 v = *(const u16x4*)(zrow + (size_t)(lb-3)*NPAD);
    #pragma unroll
    for(int cc=0;cc<4;cc++) w0[cc] = bf2f(v[cc]); }
  if(lb-2 >= 0){ u16x4 v = *(const u16x4*)(zrow + (size_t)(lb-2)*NPAD);
    #pragma unroll
    for(int cc=0;cc<4;cc++) w1[cc] = bf2f(v[cc]); }
  if(lb-1 >= 0){ u16x4 v = *(const u16x4*)(zrow + (size_t)(lb-1)*NPAD);
    #pragma unroll
    for(int cc=0;cc<4;cc++) w2[cc] = bf2f(v[cc]); }
  u16 vals[16][4];
  #pragma unroll
  for(int rr = 0; rr < 16; rr++){
    u16x4 v = *(const u16x4*)(zrow + (size_t)(lb+rr)*NPAD);
    #pragma unroll
    for(int cc = 0; cc < 4; cc++){
      float in3 = bf2f(v[cc]);
      float a = bias[cc] + w0[cc]*wt[cc][0] + w1[cc]*wt[cc][1] + w2[cc]*wt[cc][2] + in3*wt[cc][3];
      vals[rr][cc] = f2bf(a * sigmoidf_(a));
      w0[cc] = w1[cc]; w1[cc] = w2[cc]; w2[cc] = in3;
    }
  }
  if(blockIdx.x < 8){                   // x region
    #pragma unroll
    for(int rr = 0; rr < 16; rr++){
      u16x4 o; o[0]=vals[rr][0]; o[1]=vals[rr][1]; o[2]=vals[rr][2]; o[3]=vals[rr][3];
      *(u16x4*)(xq + (size_t)(b*SEQ + lb + rr) * DINNER + cbase) = o;
    }
    #pragma unroll
    for(int cc = 0; cc < 4; cc++){
      int c = cbase + cc;
      int h = c >> 6, p = c & 63;
      u16* dst = xqT + ((size_t)((b*32 + h)*64) + p) * SEQ + lb;
      u16x8 v0, v1;
      #pragma unroll
      for(int m = 0; m < 8; m++){ v0[m] = vals[m][cc]; v1[m] = vals[8+m][cc]; }
      *(u16x8*)dst = v0;
      *(u16x8*)(dst + 8) = v1;
    }
  } else {                              // B (cols 0..127) | C (cols 128..255)
    int col = cbase - 2048;
    u16* dst = (col < 128) ? Bq : Cq;
    int c4 = col & 127;
    #pragma unroll
    for(int rr = 0; rr < 16; rr++){
      u16x4 o; o[0]=vals[rr][0]; o[1]=vals[rr][1]; o[2]=vals[rr][2]; o[3]=vals[rr][3];
      *(u16x4*)(dst + (size_t)(b*SEQ + lb + rr) * 128 + c4) = o;
    }
  }
}

// ---------------- dt=softplus(dtraw+bias) + per-chunk cumsum of dt*A ----------------
__global__ __launch_bounds__(256) void k_acum(const float* __restrict__ dtraw,
                                              const float* __restrict__ dt_bias,
                                              const float* __restrict__ A_log,
                                              float* __restrict__ dtb,
                                              float* __restrict__ acum,
                                              float* __restrict__ cdec){
  int bid = blockIdx.x;               // (b*8+c)*32+h
  int h = bid & 31, c = (bid >> 5) & 7, b = bid >> 8;
  int t = threadIdx.x;
  __shared__ float sb[256];
  size_t row = (size_t)(b*SEQ + c*CHUNK + t);
  float v = dtraw[row * 128 + h] + dt_bias[h];
  float dt = (v > 20.f) ? v : log1pf(expf(v));
  dtb[row * 32 + h] = dt;
  float Ah = -expf(A_log[h]);
  float a = dt * Ah;
  sb[t] = a; __syncthreads();
  for(int off = 1; off < 256; off <<= 1){
    float vv = (t >= off) ? sb[t - off] : 0.f;
    __syncthreads();
    sb[t] += vv;
    __syncthreads();
  }
  float ac = sb[t];
  acum[(size_t)bid * 256 + t] = ac;
  if(t == 255) cdec[bid] = expf(ac);
}

// ---------------- chunk-final states (bf16 out): x^T global, decay*dt folded into B ----------------
__global__ __launch_bounds__(256) void k_states(const u16* __restrict__ xqT, const u16* __restrict__ Bq,
                                                const float* __restrict__ dtb,
                                                const float* __restrict__ acum,
                                                u16* __restrict__ states){
  int bid = blockIdx.x;               // (b*8+c)*32+h
  int h = bid & 31, c = (bid >> 5) & 7, b = bid >> 8;
  int tid = threadIdx.x;
  int w = tid >> 6, lane = tid & 63, r = lane & 15, q = lane >> 4;
  __shared__ u16 bT[128*72];          // [n][l], B * exp(alast-acum) * dt
  size_t rowB = (size_t)(b*SEQ + c*CHUNK);
  const u16* xrow = xqT + (size_t)((b*32 + h)*64) * SEQ + c*CHUNK;
  float alast = acum[(size_t)bid * 256 + 255];
  f32x4 acc[4][2] = {};
  for(int slab = 0; slab < 4; slab++){
    int lb = slab * 64;
    int l = lane;
    float f = expf(alast - acum[(size_t)bid * 256 + lb + l]) * dtb[(rowB + lb + l) * 32 + h];
    __syncthreads();
    const u16* bp = Bq + (rowB + lb + l) * 128 + w*32;
    #pragma unroll
    for(int k = 0; k < 4; k++){
      u16x8 v = *(const u16x8*)(bp + k*8);
      #pragma unroll
      for(int m = 0; m < 8; m++)
        bT[(w*32 + k*8 + m)*72 + l] = f2bf(bf2f(v[m]) * f);
    }
    __syncthreads();
    #pragma unroll
    for(int ks = 0; ks < 2; ks++){
      bf16x8 af[4], bfr[2];
      #pragma unroll
      for(int i = 0; i < 4; i++)
        af[i] = *(const bf16x8*)&xrow[(size_t)(i*16 + r) * SEQ + lb + ks*32 + q*8];
      #pragma unroll
      for(int j = 0; j < 2; j++) bfr[j] = *(const bf16x8*)&bT[(w*32 + j*16 + r)*72 + ks*32 + q*8];
      #pragma unroll
      for(int i = 0; i < 4; i++)
        #pragma unroll
        for(int j = 0; j < 2; j++)
          acc[i][j] = __builtin_amdgcn_mfma_f32_16x16x32_bf16(af[i], bfr[j], acc[i][j], 0, 0, 0);
    }
  }
  #pragma unroll
  for(int i = 0; i < 4; i++)
    #pragma unroll
    for(int j = 0; j < 2; j++)
      #pragma unroll
      for(int e = 0; e < 4; e++){
        int p = i*16 + q*4 + e;
        int n = w*32 + j*16 + r;
        states[((size_t)bid * 64 + p) * 128 + n] = f2bf(acc[i][j][e]);
      }
}

// ---------------- inter-chunk sequential scan (bf16 in, bf16 prev out) ----------------
__global__ __launch_bounds__(256) void k_scan(const u16* __restrict__ states,
                                              const float* __restrict__ cdec,
                                              u16* __restrict__ prevb){
  size_t i = (size_t)blockIdx.x * 256 + threadIdx.x;
  int n = (int)(i & 127), p = (int)((i >> 7) & 63), h = (int)((i >> 13) & 31), b = (int)(i >> 18);
  float carry = 0.f;
  for(int c = 0; c < NCHUNK; c++){
    int bch = (b*8 + c)*32 + h;
    size_t off = ((size_t)bch * 64 + p) * 128 + n;
    float s = bf2f(states[off]);
    prevb[off] = f2bf(carry);
    carry = carry * cdec[bch] + s;
  }
}

// ---------------- Y = Y_off + Y_diag (bf16 out); balanced l-tile pairs {0,3},{1,2} ----------------
__global__ __launch_bounds__(128) void k_y(const u16* __restrict__ xqT, const u16* __restrict__ Bq,
                                           const u16* __restrict__ Cq, const float* __restrict__ dtb,
                                           const float* __restrict__ acum, const u16* __restrict__ prevb,
                                           u16* __restrict__ yq){
  int bid = blockIdx.x;                 // bch*2 + pair
  int bch = bid >> 1, pr = bid & 1;
  int h = bch & 31, c = (bch >> 5) & 7, b = bch >> 8;
  int tid = threadIdx.x;
  int w2 = tid >> 6, lane = tid & 63, r = lane & 15, q = lane >> 4;
  int lt = pr ? (1 + w2) : (w2 * 3);    // pair0: {0,3}, pair1: {1,2}
  int l0 = lt * 64;
  __shared__ float acl[256];
  __shared__ float dts[256];
  __shared__ u16 G[2][64*72];
  size_t rowC = (size_t)(b*SEQ + c*CHUNK);
  #pragma unroll
  for(int it = 0; it < 2; it++){
    int s = it*128 + tid;
    acl[s] = acum[(size_t)bch * 256 + s];
    dts[s] = dtb[(rowC + s) * 32 + h];
  }
  __syncthreads();                      // only block barrier
  // C fragments
  bf16x8 cf[4][4];
  #pragma unroll
  for(int i = 0; i < 4; i++)
    #pragma unroll
    for(int ks = 0; ks < 4; ks++)
      cf[i][ks] = *(const bf16x8*)&Cq[(rowC + l0 + i*16 + r) * 128 + ks*32 + q*8];
  // Y_off = C . prev^T  (prev bf16, fragment-ready)
  f32x4 accY[4][4] = {};
  #pragma unroll
  for(int ks = 0; ks < 4; ks++){
    #pragma unroll
    for(int j = 0; j < 4; j++){
      bf16x8 bfr = *(const bf16x8*)&prevb[((size_t)bch * 64 + j*16 + r) * 128 + ks*32 + q*8];
      #pragma unroll
      for(int i = 0; i < 4; i++)
        accY[i][j] = __builtin_amdgcn_mfma_f32_16x16x32_bf16(cf[i][ks], bfr, accY[i][j], 0, 0, 0);
    }
  }
  #pragma unroll
  for(int i = 0; i < 4; i++)
    #pragma unroll
    for(int e = 0; e < 4; e++){
      float sc = expf(acl[l0 + i*16 + q*4 + e]);
      #pragma unroll
      for(int j = 0; j < 4; j++) accY[i][j][e] *= sc;
    }
  // diagonal blocks
  const u16* xrow = xqT + (size_t)((b*32 + h)*64) * SEQ + c*CHUNK;
  u16* Gw = G[w2];
  for(int st = 0; st <= lt; st++){
    int s0 = st * 64;
    f32x4 accS[4][4] = {};
    #pragma unroll
    for(int ks = 0; ks < 4; ks++){
      #pragma unroll
      for(int j = 0; j < 4; j++){
        bf16x8 bfr = *(const bf16x8*)&Bq[(rowC + s0 + j*16 + r) * 128 + ks*32 + q*8];
        #pragma unroll
        for(int i = 0; i < 4; i++)
          accS[i][j] = __builtin_amdgcn_mfma_f32_16x16x32_bf16(cf[i][ks], bfr, accS[i][j], 0, 0, 0);
      }
    }
    #pragma unroll
    for(int i = 0; i < 4; i++)
      #pragma unroll
      for(int j = 0; j < 4; j++)
        #pragma unroll
        for(int e = 0; e < 4; e++){
          int ll = l0 + i*16 + q*4 + e;
          int ss = s0 + j*16 + r;
          float v = (ll >= ss) ? accS[i][j][e] * expf(acl[ll] - acl[ss]) * dts[ss] : 0.f;
          Gw[(i*16 + q*4 + e)*72 + j*16 + r] = f2bf(v);
        }
    #pragma unroll
    for(int ks = 0; ks < 2; ks++){
      bf16x8 gf[4], xf[4];
      #pragma unroll
      for(int i = 0; i < 4; i++) gf[i] = *(const bf16x8*)&Gw[(i*16 + r)*72 + ks*32 + q*8];
      #pragma unroll
      for(int j = 0; j < 4; j++)
        xf[j] = *(const bf16x8*)&xrow[(size_t)(j*16 + r) * SEQ + s0 + ks*32 + q*8];
      #pragma unroll
      for(int i = 0; i < 4; i++)
        #pragma unroll
        for(int j = 0; j < 4; j++)
          accY[i][j] = __builtin_amdgcn_mfma_f32_16x16x32_bf16(gf[i], xf[j], accY[i][j], 0, 0, 0);
    }
  }
  #pragma unroll
  for(int i = 0; i < 4; i++)
    #pragma unroll
    for(int j = 0; j < 4; j++)
      #pragma unroll
      for(int e = 0; e < 4; e++){
        int ll = l0 + i*16 + q*4 + e;
        int p = j*16 + r;
        yq[(rowC + ll) * (size_t)DINNER + h*64 + p] = f2bf(accY[i][j][e]);
      }
}

// ---------------- gated RMSNorm + D*x fold, fp32 output ----------------
__global__ __launch_bounds__(256) void k_norm(const u16* __restrict__ yq, const u16* __restrict__ xq,
                                              const u16* __restrict__ zq, const float* __restrict__ Dp,
                                              const float* __restrict__ nw, float* __restrict__ out){
  int bl = blockIdx.x;
  int t = threadIdx.x;
  float Dh = Dp[t >> 3];                 // 8 cols per thread, 64 cols per head
  u16x8 yv = *(const u16x8*)(yq + (size_t)bl * DINNER + t*8);
  u16x8 xv = *(const u16x8*)(xq + (size_t)bl * DINNER + t*8);
  u16x8 zv = *(const u16x8*)(zq + (size_t)bl * NPAD + t*8);
  float g[8];
  float ss = 0.f;
  #pragma unroll
  for(int m = 0; m < 8; m++){
    float y = bf2f(yv[m]) + Dh * bf2f(xv[m]);
    float z = bf2f(zv[m]);
    float v = y * (z * sigmoidf_(z));
    g[m] = v;
    ss += v * v;
  }
  #pragma unroll
  for(int off = 32; off > 0; off >>= 1) ss += __shfl_down(ss, off, 64);
  __shared__ float wsum[4];
  if((t & 63) == 0) wsum[t >> 6] = ss;
  __syncthreads();
  float tot = wsum[0] + wsum[1] + wsum[2] + wsum[3];
  float scale = rsqrtf(tot / (float)DINNER + EPS);
  float4 o0, o1;
  o0.x = g[0]*scale*nw[t*8+0]; o0.y = g[1]*scale*nw[t*8+1];
  o0.z = g[2]*scale*nw[t*8+2]; o0.w = g[3]*scale*nw[t*8+3];
  o1.x = g[4]*scale*nw[t*8+4]; o1.y = g[5]*scale*nw[t*8+5];
  o1.z = g[6]*scale*nw[t*8+6]; o1.w = g[7]*scale*nw[t*8+7];
  *(float4*)(out + (size_t)bl * DINNER + t*8)     = o0;
  *(float4*)(out + (size_t)bl * DINNER + t*8 + 4) = o1;
}

extern "C" void kernel_launch(void* const* d_in, const int* in_sizes, int n_in,
                              void* d_out, int out_size, void* d_ws, size_t ws_size,
                              hipStream_t stream){
  const float* u    = (const float*)d_in[0];
  const float* W    = (const float*)d_in[1];
  const float* cw   = (const float*)d_in[2];
  const float* cb   = (const float*)d_in[3];
  const float* dtbi = (const float*)d_in[4];
  const float* Alog = (const float*)d_in[5];
  const float* Dp   = (const float*)d_in[6];
  const float* nw   = (const float*)d_in[7];
  float* out = (float*)d_out;

  char* ws = (char*)d_ws;
  size_t off = 0;
  auto alloc = [&](size_t bytes) -> void* {
    void* p = ws + off;
    off += (bytes + 255) & ~(size_t)255;
    return p;
  };
  u16*   u_bf    = (u16*)  alloc((size_t)MROWS * KDIM * 2);        //  8.4 MB
  u16*   W_bf    = (u16*)  alloc((size_t)NPAD * KDIM * 2);         //  9.2 MB
  u16*   zq      = (u16*)  alloc((size_t)MROWS * NPAD * 2);        // 36.7 MB
  float* dtraw   = (float*)alloc((size_t)MROWS * 128 * 4);         //  2.1 MB
  u16*   xq      = (u16*)  alloc((size_t)MROWS * DINNER * 2);      // 16.8 MB
  u16*   xqT     = (u16*)  alloc((size_t)MROWS * DINNER * 2);      // 16.8 MB
  u16*   Bq      = (u16*)  alloc((size_t)MROWS * 128 * 2);         //  1.0 MB
  u16*   Cq      = (u16*)  alloc((size_t)MROWS * 128 * 2);         //  1.0 MB
  float* dtb     = (float*)alloc((size_t)MROWS * 32 * 4);          //  0.5 MB
  float* acum    = (float*)alloc((size_t)512 * 256 * 4);           //  0.5 MB
  float* cdec    = (float*)alloc((size_t)512 * 4);
  u16*   states  = (u16*)  alloc((size_t)512 * 64 * 128 * 2);      //  8.4 MB
  u16*   prevb   = (u16*)  alloc((size_t)512 * 64 * 128 * 2);      //  8.4 MB
  u16*   yq      = (u16*)  alloc((size_t)MROWS * DINNER * 2);      // 16.8 MB

  k_cvt<<<4096 + 4480, 256, 0, stream>>>(u, u_bf, W, W_bf);
  k_gemm<<<35*32, 256, 0, stream>>>(u_bf, W_bf, zq, dtraw);
  k_conv<<<dim3(9, 32, 2), 256, 0, stream>>>(zq, cw, cb, xq, xqT, Bq, Cq);
  k_acum<<<512, 256, 0, stream>>>(dtraw, dtbi, Alog, dtb, acum, cdec);
  k_states<<<512, 256, 0, stream>>>(xqT, Bq, dtb, acum, states);
  k_scan<<<((size_t)BATCH*NHEADS*64*128)/256, 256, 0, stream>>>(states, cdec, prevb);
  k_y<<<1024, 128, 0, stream>>>(xqT, Bq, Cq, dtb, acum, prevb, yq);
  k_norm<<<MROWS, 256, 0, stream>>>(yq, xq, zq, Dp, nw, out);
}

// Round 6
// 275.285 us; speedup vs baseline: 1.3100x; 1.1046x over previous
//
#include <hip/hip_runtime.h>
#include <cstdint>
#include <cmath>

#define KDIM    1024
#define DPROJ   4384
#define NPAD    4480   // 4384 padded to 35*128
#define CONVDIM 2304
#define SEQ     2048
#define BATCH   2
#define MROWS   4096   // BATCH*SEQ
#define NHEADS  32
#define HEADDIM 64
#define DSTATE  128
#define CHUNK   256
#define NCHUNK  8
#define DINNER  2048
#define EPS     1e-5f
#define LOG2E   1.44269504088896f

typedef unsigned short u16;
typedef float  f32x4  __attribute__((ext_vector_type(4)));
typedef __bf16 bf16x8 __attribute__((ext_vector_type(8)));
typedef u16    u16x8  __attribute__((ext_vector_type(8)));
typedef u16    u16x4  __attribute__((ext_vector_type(4)));

__device__ __forceinline__ u16 f2bf(float f){
  unsigned u = __builtin_bit_cast(unsigned, f);
  u += 0x7fffu + ((u >> 16) & 1u);   // RNE
  return (u16)(u >> 16);
}
__device__ __forceinline__ float bf2f(u16 s){
  unsigned u = ((unsigned)s) << 16;
  return __builtin_bit_cast(float, u);
}
__device__ __forceinline__ void gl_lds16(const void* g, void* l){
  __builtin_amdgcn_global_load_lds((const __attribute__((address_space(1))) void*)g,
                                   (__attribute__((address_space(3))) void*)l, 16, 0, 0);
}
__device__ __forceinline__ float sigmoidf_(float x){ return 1.f / (1.f + expf(-x)); }

// ---------------- fp32 -> bf16 conversion (u and W merged) ----------------
__global__ __launch_bounds__(256) void k_cvt(const float* __restrict__ u_in, u16* __restrict__ u_out,
                                             const float* __restrict__ w_in, u16* __restrict__ w_out){
  int bid = blockIdx.x;
  const float* in; u16* out; size_t i; int wpath = 0;
  if(bid < 4096){ in = u_in; out = u_out; i = ((size_t)bid * 256 + threadIdx.x) * 4; }
  else          { in = w_in; out = w_out; i = ((size_t)(bid - 4096) * 256 + threadIdx.x) * 4; wpath = 1; }
  float4 v = make_float4(0.f,0.f,0.f,0.f);
  if(!wpath || (int)(i >> 10) < DPROJ) v = *(const float4*)(in + i);
  unsigned a = (unsigned)f2bf(v.x) | ((unsigned)f2bf(v.y) << 16);
  unsigned b = (unsigned)f2bf(v.z) | ((unsigned)f2bf(v.w) << 16);
  uint2 o; o.x = a; o.y = b;
  *(uint2*)(out + i) = o;
}

// ---------------- in-projection GEMM: zq = bf16(u @ W^T), BK=64, XOR-swizzled LDS ----------------
// LDS layout: row m's 16B chunk c stored at chunk-slot m*8 + (c ^ (m&7)).
// Staging picks global chunk cg = (tid&7)^((tid>>3)&7) so the HW lane->LDS mapping lands right.
// Read bank base = (c^(r&7))*4 -> 2-way only (free). Grid 1152: xcd=gid&7, 2x4 tile regions.
__global__ __launch_bounds__(256) void k_gemm(const u16* __restrict__ A, const u16* __restrict__ B,
                                              u16* __restrict__ zq, float* __restrict__ dtraw){
  __shared__ u16 As[128*64];
  __shared__ u16 Bs[128*64];
  int tid = threadIdx.x;
  int gid = blockIdx.x;
  int xcd = gid & 7, idx = gid >> 3;          // assumes round-robin block->XCD
  int xm = xcd >> 2, xn = xcd & 3;            // 2 x 4 XCD regions
  int mblk = xm*16 + (idx & 15);
  int nblk = xn*9  + (idx >> 4);
  if(nblk >= 35) return;                      // padded region (uniform exit, pre-barrier)
  int m0 = mblk * 128, n0 = nblk * 128;
  int w = tid >> 6, lane = tid & 63, r = lane & 15, q = lane >> 4;
  int wm = (w >> 1) * 64, wn = (w & 1) * 64;
  f32x4 acc[4][4] = {};
  int cg = (tid & 7) ^ ((tid >> 3) & 7);      // swizzled source chunk
  const u16* Ag = A + (size_t)(m0 + (tid >> 3)) * KDIM + cg * 8;
  const u16* Bg = B + (size_t)(n0 + (tid >> 3)) * KDIM + cg * 8;
  for(int kt = 0; kt < KDIM/64; kt++){
    int k0 = kt * 64;
    #pragma unroll
    for(int m = 0; m < 4; m++){
      gl_lds16(Ag + (size_t)m*32*KDIM + k0, &As[((size_t)m*256 + tid) * 8]);
      gl_lds16(Bg + (size_t)m*32*KDIM + k0, &Bs[((size_t)m*256 + tid) * 8]);
    }
    __syncthreads();
    #pragma unroll
    for(int ks = 0; ks < 2; ks++){
      int ca = ((ks*4 + q) ^ (r & 7)) * 8;    // swizzled chunk offset for this lane
      bf16x8 af[4], bfm[4];
      #pragma unroll
      for(int i = 0; i < 4; i++) af[i]  = *(const bf16x8*)&As[(wm + i*16 + r) * 64 + ca];
      #pragma unroll
      for(int j = 0; j < 4; j++) bfm[j] = *(const bf16x8*)&Bs[(wn + j*16 + r) * 64 + ca];
      #pragma unroll
      for(int i = 0; i < 4; i++)
        #pragma unroll
        for(int j = 0; j < 4; j++)
          acc[i][j] = __builtin_amdgcn_mfma_f32_16x16x32_bf16(af[i], bfm[j], acc[i][j], 0, 0, 0);
    }
    __syncthreads();
  }
  #pragma unroll
  for(int i = 0; i < 4; i++)
    #pragma unroll
    for(int j = 0; j < 4; j++)
      #pragma unroll
      for(int e = 0; e < 4; e++){
        int row = m0 + wm + i*16 + q*4 + e;
        int col = n0 + wn + j*16 + r;
        zq[(size_t)row * NPAD + col] = f2bf(acc[i][j][e]);
        if(nblk == 34) dtraw[(size_t)row * 128 + (col - 4352)] = acc[i][j][e];
      }
}

// ---------------- conv1d + silu + split; 4 consecutive c per thread (coalesced) ----------------
__global__ __launch_bounds__(256) void k_conv(const u16* __restrict__ zq,
                                              const float* __restrict__ cw,
                                              const float* __restrict__ cb,
                                              u16* __restrict__ xq, u16* __restrict__ xqT,
                                              u16* __restrict__ Bq, u16* __restrict__ Cq){
  int c0 = blockIdx.x * 256;            // 9 c-tiles over CONVDIM (tile 8 == B|C)
  int l0 = blockIdx.y * 64;             // 32 l-tiles over SEQ
  int b  = blockIdx.z;
  int tid = threadIdx.x;
  int cbase = c0 + (tid & 63) * 4;      // 4 consecutive channels
  int lb = l0 + (tid >> 6) * 16;        // 16 rows
  float wt[4][4], bias[4];
  #pragma unroll
  for(int cc = 0; cc < 4; cc++){
    float4 wv = *(const float4*)(cw + (cbase + cc)*4);
    wt[cc][0]=wv.x; wt[cc][1]=wv.y; wt[cc][2]=wv.z; wt[cc][3]=wv.w;
    bias[cc] = cb[cbase + cc];
  }
  const u16* zrow = zq + (size_t)(b*SEQ) * NPAD + 2048 + cbase;
  float w0[4] = {}, w1[4] = {}, w2[4] = {};
  if(lb-3 >= 0){ u16x4 v = *(const u16x4*)(zrow + (size_t)(lb-3)*NPAD);
    #pragma unroll
    for(int cc=0;cc<4;cc++) w0[cc] = bf2f(v[cc]); }
  if(lb-2 >= 0){ u16x4 v = *(const u16x4*)(zrow + (size_t)(lb-2)*NPAD);
    #pragma unroll
    for(int cc=0;cc<4;cc++) w1[cc] = bf2f(v[cc]); }
  if(lb-1 >= 0){ u16x4 v = *(const u16x4*)(zrow + (size_t)(lb-1)*NPAD);
    #pragma unroll
    for(int cc=0;cc<4;cc++) w2[cc] = bf2f(v[cc]); }
  u16 vals[16][4];
  #pragma unroll
  for(int rr = 0; rr < 16; rr++){
    u16x4 v = *(const u16x4*)(zrow + (size_t)(lb+rr)*NPAD);
    #pragma unroll
    for(int cc = 0; cc < 4; cc++){
      float in3 = bf2f(v[cc]);
      float a = bias[cc] + w0[cc]*wt[cc][0] + w1[cc]*wt[cc][1] + w2[cc]*wt[cc][2] + in3*wt[cc][3];
      vals[rr][cc] = f2bf(a * sigmoidf_(a));
      w0[cc] = w1[cc]; w1[cc] = w2[cc]; w2[cc] = in3;
    }
  }
  if(blockIdx.x < 8){                   // x region
    #pragma unroll
    for(int rr = 0; rr < 16; rr++){
      u16x4 o; o[0]=vals[rr][0]; o[1]=vals[rr][1]; o[2]=vals[rr][2]; o[3]=vals[rr][3];
      *(u16x4*)(xq + (size_t)(b*SEQ + lb + rr) * DINNER + cbase) = o;
    }
    #pragma unroll
    for(int cc = 0; cc < 4; cc++){
      int c = cbase + cc;
      int h = c >> 6, p = c & 63;
      u16* dst = xqT + ((size_t)((b*32 + h)*64) + p) * SEQ + lb;
      u16x8 v0, v1;
      #pragma unroll
      for(int m = 0; m < 8; m++){ v0[m] = vals[m][cc]; v1[m] = vals[8+m][cc]; }
      *(u16x8*)dst = v0;
      *(u16x8*)(dst + 8) = v1;
    }
  } else {                              // B (cols 0..127) | C (cols 128..255)
    int col = cbase - 2048;
    u16* dst = (col < 128) ? Bq : Cq;
    int c4 = col & 127;
    #pragma unroll
    for(int rr = 0; rr < 16; rr++){
      u16x4 o; o[0]=vals[rr][0]; o[1]=vals[rr][1]; o[2]=vals[rr][2]; o[3]=vals[rr][3];
      *(u16x4*)(dst + (size_t)(b*SEQ + lb + rr) * 128 + c4) = o;
    }
  }
}

// ---------------- dt=softplus(dtraw+bias) + per-chunk cumsum of dt*A ----------------
__global__ __launch_bounds__(256) void k_acum(const float* __restrict__ dtraw,
                                              const float* __restrict__ dt_bias,
                                              const float* __restrict__ A_log,
                                              float* __restrict__ dtb,
                                              float* __restrict__ acum,
                                              float* __restrict__ cdec){
  int bid = blockIdx.x;               // (b*8+c)*32+h
  int h = bid & 31, c = (bid >> 5) & 7, b = bid >> 8;
  int t = threadIdx.x;
  __shared__ float sb[256];
  size_t row = (size_t)(b*SEQ + c*CHUNK + t);
  float v = dtraw[row * 128 + h] + dt_bias[h];
  float dt = (v > 20.f) ? v : log1pf(expf(v));
  dtb[row * 32 + h] = dt;
  float Ah = -expf(A_log[h]);
  float a = dt * Ah;
  sb[t] = a; __syncthreads();
  for(int off = 1; off < 256; off <<= 1){
    float vv = (t >= off) ? sb[t - off] : 0.f;
    __syncthreads();
    sb[t] += vv;
    __syncthreads();
  }
  float ac = sb[t];
  acum[(size_t)bid * 256 + t] = ac;
  if(t == 255) cdec[bid] = exp2f(ac * LOG2E);
}

// ---------------- chunk-final states (bf16 out): x^T global, decay*dt folded into B ----------------
__global__ __launch_bounds__(256) void k_states(const u16* __restrict__ xqT, const u16* __restrict__ Bq,
                                                const float* __restrict__ dtb,
                                                const float* __restrict__ acum,
                                                u16* __restrict__ states){
  int bid = blockIdx.x;               // (b*8+c)*32+h
  int h = bid & 31, c = (bid >> 5) & 7, b = bid >> 8;
  int tid = threadIdx.x;
  int w = tid >> 6, lane = tid & 63, r = lane & 15, q = lane >> 4;
  __shared__ u16 bT[128*72];          // [n][l], B * exp(alast-acum) * dt
  size_t rowB = (size_t)(b*SEQ + c*CHUNK);
  const u16* xrow = xqT + (size_t)((b*32 + h)*64) * SEQ + c*CHUNK;
  float alast = acum[(size_t)bid * 256 + 255];
  f32x4 acc[4][2] = {};
  for(int slab = 0; slab < 4; slab++){
    int lb = slab * 64;
    int l = lane;
    float f = exp2f((alast - acum[(size_t)bid * 256 + lb + l]) * LOG2E) * dtb[(rowB + lb + l) * 32 + h];
    __syncthreads();
    const u16* bp = Bq + (rowB + lb + l) * 128 + w*32;
    #pragma unroll
    for(int k = 0; k < 4; k++){
      u16x8 v = *(const u16x8*)(bp + k*8);
      #pragma unroll
      for(int m = 0; m < 8; m++)
        bT[(w*32 + k*8 + m)*72 + l] = f2bf(bf2f(v[m]) * f);
    }
    __syncthreads();
    #pragma unroll
    for(int ks = 0; ks < 2; ks++){
      bf16x8 af[4], bfr[2];
      #pragma unroll
      for(int i = 0; i < 4; i++)
        af[i] = *(const bf16x8*)&xrow[(size_t)(i*16 + r) * SEQ + lb + ks*32 + q*8];
      #pragma unroll
      for(int j = 0; j < 2; j++) bfr[j] = *(const bf16x8*)&bT[(w*32 + j*16 + r)*72 + ks*32 + q*8];
      #pragma unroll
      for(int i = 0; i < 4; i++)
        #pragma unroll
        for(int j = 0; j < 2; j++)
          acc[i][j] = __builtin_amdgcn_mfma_f32_16x16x32_bf16(af[i], bfr[j], acc[i][j], 0, 0, 0);
    }
  }
  #pragma unroll
  for(int i = 0; i < 4; i++)
    #pragma unroll
    for(int j = 0; j < 2; j++)
      #pragma unroll
      for(int e = 0; e < 4; e++){
        int p = i*16 + q*4 + e;
        int n = w*32 + j*16 + r;
        states[((size_t)bid * 64 + p) * 128 + n] = f2bf(acc[i][j][e]);
      }
}

// ---------------- inter-chunk sequential scan (bf16 in, bf16 prev out) ----------------
__global__ __launch_bounds__(256) void k_scan(const u16* __restrict__ states,
                                              const float* __restrict__ cdec,
                                              u16* __restrict__ prevb){
  size_t i = (size_t)blockIdx.x * 256 + threadIdx.x;
  int n = (int)(i & 127), p = (int)((i >> 7) & 63), h = (int)((i >> 13) & 31), b = (int)(i >> 18);
  float carry = 0.f;
  for(int c = 0; c < NCHUNK; c++){
    int bch = (b*8 + c)*32 + h;
    size_t off = ((size_t)bch * 64 + p) * 128 + n;
    float s = bf2f(states[off]);
    prevb[off] = f2bf(carry);
    carry = carry * cdec[bch] + s;
  }
}

// ---------------- Y = Y_off + Y_diag (bf16 out); ONE WAVE per (bch, l-tile) ----------------
// Zero barriers: LDS is wave-private; in-wave DS ordering handles G RAW/WAR.
// Decay in log2 domain: acl2 = acum*log2e -> exp2f (single v_exp_f32).
__global__ __launch_bounds__(64) void k_y(const u16* __restrict__ xqT, const u16* __restrict__ Bq,
                                          const u16* __restrict__ Cq, const float* __restrict__ dtb,
                                          const float* __restrict__ acum, const u16* __restrict__ prevb,
                                          u16* __restrict__ yq){
  int bid = blockIdx.x;                 // bch*4 + lt
  int lt = bid & 3, bch = bid >> 2;
  int h = bch & 31, c = (bch >> 5) & 7, b = bch >> 8;
  int t = threadIdx.x, r = t & 15, q = t >> 4;
  int l0 = lt * 64;
  __shared__ float acl2[256];
  __shared__ float dts[256];
  __shared__ u16 G[64*72];
  size_t rowC = (size_t)(b*SEQ + c*CHUNK);
  #pragma unroll
  for(int it = 0; it < 4; it++){
    int s = it*64 + t;
    acl2[s] = acum[(size_t)bch * 256 + s] * LOG2E;
    dts[s] = dtb[(rowC + s) * 32 + h];
  }
  // C fragments (reused by Y_off and all s-tiles)
  bf16x8 cf[4][4];
  #pragma unroll
  for(int i = 0; i < 4; i++)
    #pragma unroll
    for(int ks = 0; ks < 4; ks++)
      cf[i][ks] = *(const bf16x8*)&Cq[(rowC + l0 + i*16 + r) * 128 + ks*32 + q*8];
  // Y_off = C . prev^T
  f32x4 accY[4][4] = {};
  #pragma unroll
  for(int ks = 0; ks < 4; ks++){
    #pragma unroll
    for(int j = 0; j < 4; j++){
      bf16x8 bfr = *(const bf16x8*)&prevb[((size_t)bch * 64 + j*16 + r) * 128 + ks*32 + q*8];
      #pragma unroll
      for(int i = 0; i < 4; i++)
        accY[i][j] = __builtin_amdgcn_mfma_f32_16x16x32_bf16(cf[i][ks], bfr, accY[i][j], 0, 0, 0);
    }
  }
  #pragma unroll
  for(int i = 0; i < 4; i++)
    #pragma unroll
    for(int e = 0; e < 4; e++){
      float sc = exp2f(acl2[l0 + i*16 + q*4 + e]);
      #pragma unroll
      for(int j = 0; j < 4; j++) accY[i][j][e] *= sc;
    }
  // diagonal blocks: S = C.B^T; G = decay(S)*dt; Y += G.x^T
  const u16* xrow = xqT + (size_t)((b*32 + h)*64) * SEQ + c*CHUNK;
  for(int st = 0; st <= lt; st++){
    int s0 = st * 64;
    f32x4 accS[4][4] = {};
    #pragma unroll
    for(int ks = 0; ks < 4; ks++){
      #pragma unroll
      for(int j = 0; j < 4; j++){
        bf16x8 bfr = *(const bf16x8*)&Bq[(rowC + s0 + j*16 + r) * 128 + ks*32 + q*8];
        #pragma unroll
        for(int i = 0; i < 4; i++)
          accS[i][j] = __builtin_amdgcn_mfma_f32_16x16x32_bf16(cf[i][ks], bfr, accS[i][j], 0, 0, 0);
      }
    }
    float aS[4], dS[4];
    #pragma unroll
    for(int j = 0; j < 4; j++){ aS[j] = acl2[s0 + j*16 + r]; dS[j] = dts[s0 + j*16 + r]; }
    if(st < lt){                         // strictly-below tiles: no mask needed
      #pragma unroll
      for(int i = 0; i < 4; i++)
        #pragma unroll
        for(int e = 0; e < 4; e++){
          float aL = acl2[l0 + i*16 + q*4 + e];
          #pragma unroll
          for(int j = 0; j < 4; j++){
            float v = accS[i][j][e] * exp2f(aL - aS[j]) * dS[j];
            G[(i*16 + q*4 + e)*72 + j*16 + r] = f2bf(v);
          }
        }
    } else {                             // diagonal tile: causal mask
      #pragma unroll
      for(int i = 0; i < 4; i++)
        #pragma unroll
        for(int e = 0; e < 4; e++){
          int ll = i*16 + q*4 + e;
          float aL = acl2[l0 + ll];
          #pragma unroll
          for(int j = 0; j < 4; j++){
            int ss = j*16 + r;
            float v = (ll >= ss) ? accS[i][j][e] * exp2f(aL - aS[j]) * dS[j] : 0.f;
            G[(i*16 + q*4 + e)*72 + j*16 + r] = f2bf(v);
          }
        }
    }
    #pragma unroll
    for(int ks = 0; ks < 2; ks++){
      bf16x8 gf[4], xf[4];
      #pragma unroll
      for(int i = 0; i < 4; i++) gf[i] = *(const bf16x8*)&G[(i*16 + r)*72 + ks*32 + q*8];
      #pragma unroll
      for(int j = 0; j < 4; j++)
        xf[j] = *(const bf16x8*)&xrow[(size_t)(j*16 + r) * SEQ + s0 + ks*32 + q*8];
      #pragma unroll
      for(int i = 0; i < 4; i++)
        #pragma unroll
        for(int j = 0; j < 4; j++)
          accY[i][j] = __builtin_amdgcn_mfma_f32_16x16x32_bf16(gf[i], xf[j], accY[i][j], 0, 0, 0);
    }
  }
  #pragma unroll
  for(int i = 0; i < 4; i++)
    #pragma unroll
    for(int j = 0; j < 4; j++)
      #pragma unroll
      for(int e = 0; e < 4; e++){
        int ll = l0 + i*16 + q*4 + e;
        int p = j*16 + r;
        yq[(rowC + ll) * (size_t)DINNER + h*64 + p] = f2bf(accY[i][j][e]);
      }
}

// ---------------- gated RMSNorm + D*x fold, fp32 output ----------------
__global__ __launch_bounds__(256) void k_norm(const u16* __restrict__ yq, const u16* __restrict__ xq,
                                              const u16* __restrict__ zq, const float* __restrict__ Dp,
                                              const float* __restrict__ nw, float* __restrict__ out){
  int bl = blockIdx.x;
  int t = threadIdx.x;
  float Dh = Dp[t >> 3];                 // 8 cols per thread, 64 cols per head
  u16x8 yv = *(const u16x8*)(yq + (size_t)bl * DINNER + t*8);
  u16x8 xv = *(const u16x8*)(xq + (size_t)bl * DINNER + t*8);
  u16x8 zv = *(const u16x8*)(zq + (size_t)bl * NPAD + t*8);
  float g[8];
  float ss = 0.f;
  #pragma unroll
  for(int m = 0; m < 8; m++){
    float y = bf2f(yv[m]) + Dh * bf2f(xv[m]);
    float z = bf2f(zv[m]);
    float v = y * (z * sigmoidf_(z));
    g[m] = v;
    ss += v * v;
  }
  #pragma unroll
  for(int off = 32; off > 0; off >>= 1) ss += __shfl_down(ss, off, 64);
  __shared__ float wsum[4];
  if((t & 63) == 0) wsum[t >> 6] = ss;
  __syncthreads();
  float tot = wsum[0] + wsum[1] + wsum[2] + wsum[3];
  float scale = rsqrtf(tot / (float)DINNER + EPS);
  float4 o0, o1;
  o0.x = g[0]*scale*nw[t*8+0]; o0.y = g[1]*scale*nw[t*8+1];
  o0.z = g[2]*scale*nw[t*8+2]; o0.w = g[3]*scale*nw[t*8+3];
  o1.x = g[4]*scale*nw[t*8+4]; o1.y = g[5]*scale*nw[t*8+5];
  o1.z = g[6]*scale*nw[t*8+6]; o1.w = g[7]*scale*nw[t*8+7];
  *(float4*)(out + (size_t)bl * DINNER + t*8)     = o0;
  *(float4*)(out + (size_t)bl * DINNER + t*8 + 4) = o1;
}

extern "C" void kernel_launch(void* const* d_in, const int* in_sizes, int n_in,
                              void* d_out, int out_size, void* d_ws, size_t ws_size,
                              hipStream_t stream){
  const float* u    = (const float*)d_in[0];
  const float* W    = (const float*)d_in[1];
  const float* cw   = (const float*)d_in[2];
  const float* cb   = (const float*)d_in[3];
  const float* dtbi = (const float*)d_in[4];
  const float* Alog = (const float*)d_in[5];
  const float* Dp   = (const float*)d_in[6];
  const float* nw   = (const float*)d_in[7];
  float* out = (float*)d_out;

  char* ws = (char*)d_ws;
  size_t off = 0;
  auto alloc = [&](size_t bytes) -> void* {
    void* p = ws + off;
    off += (bytes + 255) & ~(size_t)255;
    return p;
  };
  u16*   u_bf    = (u16*)  alloc((size_t)MROWS * KDIM * 2);        //  8.4 MB
  u16*   W_bf    = (u16*)  alloc((size_t)NPAD * KDIM * 2);         //  9.2 MB
  u16*   zq      = (u16*)  alloc((size_t)MROWS * NPAD * 2);        // 36.7 MB
  float* dtraw   = (float*)alloc((size_t)MROWS * 128 * 4);         //  2.1 MB
  u16*   xq      = (u16*)  alloc((size_t)MROWS * DINNER * 2);      // 16.8 MB
  u16*   xqT     = (u16*)  alloc((size_t)MROWS * DINNER * 2);      // 16.8 MB
  u16*   Bq      = (u16*)  alloc((size_t)MROWS * 128 * 2);         //  1.0 MB
  u16*   Cq      = (u16*)  alloc((size_t)MROWS * 128 * 2);         //  1.0 MB
  float* dtb     = (float*)alloc((size_t)MROWS * 32 * 4);          //  0.5 MB
  float* acum    = (float*)alloc((size_t)512 * 256 * 4);           //  0.5 MB
  float* cdec    = (float*)alloc((size_t)512 * 4);
  u16*   states  = (u16*)  alloc((size_t)512 * 64 * 128 * 2);      //  8.4 MB
  u16*   prevb   = (u16*)  alloc((size_t)512 * 64 * 128 * 2);      //  8.4 MB
  u16*   yq      = (u16*)  alloc((size_t)MROWS * DINNER * 2);      // 16.8 MB

  k_cvt<<<4096 + 4480, 256, 0, stream>>>(u, u_bf, W, W_bf);
  k_gemm<<<1152, 256, 0, stream>>>(u_bf, W_bf, zq, dtraw);
  k_conv<<<dim3(9, 32, 2), 256, 0, stream>>>(zq, cw, cb, xq, xqT, Bq, Cq);
  k_acum<<<512, 256, 0, stream>>>(dtraw, dtbi, Alog, dtb, acum, cdec);
  k_states<<<512, 256, 0, stream>>>(xqT, Bq, dtb, acum, states);
  k_scan<<<((size_t)BATCH*NHEADS*64*128)/256, 256, 0, stream>>>(states, cdec, prevb);
  k_y<<<2048, 64, 0, stream>>>(xqT, Bq, Cq, dtb, acum, prevb, yq);
  k_norm<<<MROWS, 256, 0, stream>>>(yq, xq, zq, Dp, nw, out);
}